// Round 21
// baseline (794.279 us; speedup 1.0000x reference)
//
#include <hip/hip_runtime.h>

#define NBATCH 4
#define NATOM 1024
#define NSEL 128
#define H1 25
#define H2 50
#define HM 100
#define AX 16
#define GF 1600
#define FI 240
#define NT 2
#define NGRP64 18   // 64-atom type-pure groups per batch (1152/64)
#define PCH 5       // N-chunks for k_pm (20 ntiles each)

// ---- workspace layout (float/uint offsets) ----
#define WS_STATS_RAW 0
#define WS_STATS_FIN 64      // [avg_s, inv_ss, inv_sx, cntf, rawcnt]
#define WS_MUSD_RAW 128
#define WS_MUSD_FIN 144
#define WS_S_RAW 176
#define WS_CTR 192
#define WS_EBUF 256
#define WS_IDX (WS_EBUF + NBATCH*NATOM)                  // ints, per-batch type-sorted, 1152/batch
#define WS_G (WS_IDX + NBATCH*1152)
#define WS_P (WS_G + (size_t)NBATCH*NATOM*GF)
// MFMA B-fragment packs for fit net:
#define WS_BP0  (WS_P + (size_t)NBATCH*NATOM*GF)         // [t][15][50][64][4]  L0 (gw0)
#define WS_BP1  (WS_BP0 + (size_t)NT*15*50*256)          // [t][15][8][64][4]   L1 (gw1)
#define WS_BP2  (WS_BP1 + (size_t)NT*15*8*256)           // L2 (gw2)
#define WS_BPT2 (WS_BP2 + (size_t)NT*15*8*256)           // dz2 (gw2^T)
#define WS_BPT1 (WS_BPT2 + (size_t)NT*15*8*256)          // dz1 (gw1^T)
#define WS_BPT0 (WS_BPT1 + (size_t)NT*15*8*256)          // [t][100][8][64][4]  p (gw0^T)
#define WS_FW1T (WS_BPT0 + (size_t)NT*100*8*256)         // fp32 filter transposes
#define WS_FW2T (WS_FW1T + (size_t)NT*H2*H1)
#define WS_RGB (WS_FW2T + (size_t)NT*HM*H2)              // RG store: NBATCH*NATOM*400
#define WS_GTB (WS_RGB + (size_t)NBATCH*NATOM*HM*4)      // GT-packed bf16 G: [atom][HM/2][NSEL]
#define WS_GTB_UNITS ((size_t)NBATCH*NATOM*(HM/2)*NSEL)
// filter-net B-frag packs:
#define WS_BF1B  (WS_GTB + WS_GTB_UNITS)                 // [t][4nt][64][4]      a2 fwd (fw1)
#define WS_BW2TB (WS_BF1B + (size_t)NT*1024)             // [t][4nt][4ks][64][4] dz2 (fw2^T)
#define WS_BW1TB (WS_BW2TB + (size_t)NT*4096)            // [t][2nt][2ks][64][4] dz1 (fw1^T)
#define WS_BF2B  (WS_BW1TB + (size_t)NT*1024)            // [t][7nt][2ks][64][4] G fwd (fw2)
#define WS_DZ1  (WS_BF2B + (size_t)NT*3584)              // dz1 frag images: [72 groups][8448 uints]
#define WS_END  (WS_DZ1 + (size_t)NBATCH*NGRP64*8448)

#define GSTR 108   // ushort stride for G in LDS

typedef __attribute__((ext_vector_type(8))) short bf16x8;
typedef __attribute__((ext_vector_type(4))) float f32x4;

__device__ __forceinline__ float ftanh(float x){
  float e = __expf(2.0f*x);
  return 1.0f - 2.0f/(e+1.0f);
}
__device__ __forceinline__ unsigned short f2bf(float x){
  unsigned b=__float_as_uint(x); b += 0x7FFF + ((b>>16)&1); return (unsigned short)(b>>16);
}
__device__ __forceinline__ float bf2f(unsigned short h){ return __uint_as_float(((unsigned)h)<<16); }
__device__ __forceinline__ float bflo(unsigned u){ return __uint_as_float(u<<16); }
__device__ __forceinline__ float bfhi(unsigned u){ return __uint_as_float(u & 0xFFFF0000u); }
__device__ __forceinline__ unsigned packbf(float a, float b){
  return (unsigned)f2bf(a) | ((unsigned)f2bf(b)<<16);
}

__device__ __forceinline__ float wave_sum(float v){
#pragma unroll
  for(int o=32;o>0;o>>=1) v += __shfl_down(v,o,64);
  return v;
}
__device__ __forceinline__ float block_sum2(float v, float* red){
  v = wave_sum(v);
  __syncthreads();
  if((threadIdx.x&63)==0) red[threadIdx.x>>6]=v;
  __syncthreads();
  return red[0]+red[1];
}
__device__ __forceinline__ float block_sum4(float v, float* red){
  v = wave_sum(v);
  __syncthreads();
  if((threadIdx.x&63)==0) red[threadIdx.x>>6]=v;
  __syncthreads();
  return red[0]+red[1]+red[2]+red[3];
}

// ---- pack fit-net MFMA B-fragments (bf16) + fp32 filter transposes ----
__global__ void __launch_bounds__(256) k_transpose(const float* __restrict__ gw0,
    const float* __restrict__ gw1, const float* __restrict__ gw2,
    const float* __restrict__ fw1, const float* __restrict__ fw2, float* __restrict__ ws){
  const int cB0 = NT*15*50*256;
  const int cB1 = NT*15*8*256;
  const int cT0 = NT*100*8*256;
  const int c6 = NT*H2*H1, c7 = NT*HM*H2;
  const int total = cB0 + 4*cB1 + cT0 + c6 + c7;
  unsigned* wsu = (unsigned*)ws;
  for(int i = blockIdx.x*blockDim.x + threadIdx.x; i < total; i += gridDim.x*blockDim.x){
    if(i < cB0 + 4*cB1 + cT0){
      int base, NKs; const float* W; int KK; int mode; int t;
      int ii = i;
      if(ii < cB0){ base=WS_BP0; NKs=50; KK=1600; mode=0; t = ii/(15*50*256); ii -= t*(15*50*256); W = gw0 + (size_t)t*GF*FI; }
      else if(ii < cB0+cB1){ ii-=cB0; base=WS_BP1; NKs=8; KK=240; mode=0; t = ii/(15*8*256); ii -= t*(15*8*256); W = gw1 + t*FI*FI; }
      else if(ii < cB0+2*cB1){ ii-=cB0+cB1; base=WS_BP2; NKs=8; KK=240; mode=0; t = ii/(15*8*256); ii -= t*(15*8*256); W = gw2 + t*FI*FI; }
      else if(ii < cB0+3*cB1){ ii-=cB0+2*cB1; base=WS_BPT2; NKs=8; KK=240; mode=1; t = ii/(15*8*256); ii -= t*(15*8*256); W = gw2 + t*FI*FI; }
      else if(ii < cB0+4*cB1){ ii-=cB0+3*cB1; base=WS_BPT1; NKs=8; KK=240; mode=1; t = ii/(15*8*256); ii -= t*(15*8*256); W = gw1 + t*FI*FI; }
      else { ii-=cB0+4*cB1; base=WS_BPT0; NKs=8; KK=240; mode=2; t = ii/(100*8*256); ii -= t*(100*8*256); W = gw0 + (size_t)t*GF*FI; }
      int d = ii & 3;
      int lane = (ii>>2) & 63;
      int rem = ii >> 8;
      int ks = rem % NKs;
      int ntile = rem / NKs;
      int n = ntile*16 + (lane&15);
      int k0 = ks*32 + ((lane>>4)&3)*8 + 2*d;
      float v0, v1;
      if(mode==0){
        v0 = (k0   < KK) ? W[(size_t)(k0  )*FI + n] : 0.f;
        v1 = (k0+1 < KK) ? W[(size_t)(k0+1)*FI + n] : 0.f;
      } else if(mode==1){
        v0 = (k0   < KK) ? W[n*FI + k0  ] : 0.f;
        v1 = (k0+1 < KK) ? W[n*FI + k0+1] : 0.f;
      } else {
        v0 = (k0   < KK) ? W[(size_t)n*FI + k0  ] : 0.f;
        v1 = (k0+1 < KK) ? W[(size_t)n*FI + k0+1] : 0.f;
      }
      int telems = (base==WS_BP0) ? 15*50*256 : (base==WS_BPT0 ? 100*8*256 : 15*8*256);
      wsu[base + (size_t)t*telems + ii] = packbf(v0, v1);
    } else if(i < cB0 + 4*cB1 + cT0 + c6){
      int ii = i - (cB0+4*cB1+cT0); int t = ii/(H2*H1); int rem = ii - t*(H2*H1);
      int j = rem/H1; int k = rem - j*H1;
      ws[WS_FW1T + ii] = fw1[t*H1*H2 + k*H2 + j];
    } else {
      int ii = i - (cB0+4*cB1+cT0+c6); int t = ii/(HM*H2); int rem = ii - t*(HM*H2);
      int m = rem/H2; int j = rem - m*H2;
      ws[WS_FW2T + ii] = fw2[t*H2*HM + j*HM + m];
    }
  }
}

// ---- pack filter-net B-fragments for k_bwdm2 / k_fwdm ----
__global__ void __launch_bounds__(256) k_packf(const float* __restrict__ fw1,
    const float* __restrict__ fw2, float* __restrict__ ws){
  unsigned* wsu = (unsigned*)ws;
  const int c1 = NT*1024, c2 = NT*4096, c3 = NT*1024, c4 = NT*3584;
  const int total = c1 + c2 + c3 + c4;
  for(int i = blockIdx.x*blockDim.x + threadIdx.x; i < total; i += gridDim.x*blockDim.x){
    if(i < c1){                      // BF1
      int t = i/1024; int ii = i - t*1024;
      int nt = ii>>8; int lane = (ii>>2)&63; int d = ii&3;
      int n = nt*16 + (lane&15);
      int k0 = ((lane>>4)&3)*8 + 2*d;
      float v0 = (k0   < H1 && n < H2) ? fw1[t*H1*H2 + (k0  )*H2 + n] : 0.f;
      float v1 = (k0+1 < H1 && n < H2) ? fw1[t*H1*H2 + (k0+1)*H2 + n] : 0.f;
      wsu[WS_BF1B + i] = packbf(v0, v1);
    } else if(i < c1 + c2){          // BW2T
      int ii = i - c1; int t = ii/4096; ii -= t*4096;
      int nt = ii>>10; int ks = (ii>>8)&3; int lane = (ii>>2)&63; int d = ii&3;
      int n = nt*16 + (lane&15);
      int k0 = ks*32 + ((lane>>4)&3)*8 + 2*d;
      float v0 = (k0   < HM && n < H2) ? fw2[t*H2*HM + n*HM + k0  ] : 0.f;
      float v1 = (k0+1 < HM && n < H2) ? fw2[t*H2*HM + n*HM + k0+1] : 0.f;
      wsu[WS_BW2TB + ii + t*4096] = packbf(v0, v1);
    } else if(i < c1 + c2 + c3){     // BW1T
      int ii = i - c1 - c2; int t = ii/1024; ii -= t*1024;
      int nt = ii>>9; int ks = (ii>>8)&1; int lane = (ii>>2)&63; int d = ii&3;
      int n = nt*16 + (lane&15);
      int k0 = ks*32 + ((lane>>4)&3)*8 + 2*d;
      float v0 = (k0   < H2 && n < H1) ? fw1[t*H1*H2 + n*H2 + k0  ] : 0.f;
      float v1 = (k0+1 < H2 && n < H1) ? fw1[t*H1*H2 + n*H2 + k0+1] : 0.f;
      wsu[WS_BW1TB + ii + t*1024] = packbf(v0, v1);
    } else {                         // BF2
      int ii = i - c1 - c2 - c3; int t = ii/3584; ii -= t*3584;
      int nt = ii>>9; int ks = (ii>>8)&1; int lane = (ii>>2)&63; int d = ii&3;
      int n = nt*16 + (lane&15);
      int k0 = ks*32 + ((lane>>4)&3)*8 + 2*d;
      float v0 = (k0   < H2 && n < HM) ? fw2[t*H2*HM + (k0  )*HM + n] : 0.f;
      float v1 = (k0+1 < H2 && n < HM) ? fw2[t*H2*HM + (k0+1)*HM + n] : 0.f;
      wsu[WS_BF2B + ii + t*3584] = packbf(v0, v1);
    }
  }
}

__global__ void __launch_bounds__(256) k_stats(const float* __restrict__ sym,
    const int* __restrict__ types, float* __restrict__ ws){
  const int b = blockIdx.y;
  const int n0 = blockIdx.x * 64;
  const float* R = sym + ((size_t)b*NATOM + n0)*NSEL*4;
  const int* ty = types + b*NATOM;
  float ss0=0,ss20=0,xs0=0,xs20=0,ss1=0,ss21=0,xs1=0,xs21=0,c0=0,c1=0;
  for(int idx=threadIdx.x; idx<64*NSEL*4; idx+=256){
    int a = idx >> 9;
    int t = ty[n0+a];
    float v = R[idx];
    bool iss = (idx&3)==0;
    if(t==0){ if(iss){ss0+=v;ss20+=v*v;} else {xs0+=v;xs20+=v*v;} }
    else    { if(iss){ss1+=v;ss21+=v*v;} else {xs1+=v;xs21+=v*v;} }
  }
  if(threadIdx.x<64){ if(ty[n0+threadIdx.x]==0) c0=1.f; else c1=1.f; }
  ss0=wave_sum(ss0); ss20=wave_sum(ss20); xs0=wave_sum(xs0); xs20=wave_sum(xs20); c0=wave_sum(c0);
  ss1=wave_sum(ss1); ss21=wave_sum(ss21); xs1=wave_sum(xs1); xs21=wave_sum(xs21); c1=wave_sum(c1);
  if((threadIdx.x&63)==0){
    float* r0 = ws + WS_STATS_RAW + (b*2+0)*8;
    float* r1 = ws + WS_STATS_RAW + (b*2+1)*8;
    atomicAdd(r0+0,c0); atomicAdd(r0+1,ss0); atomicAdd(r0+2,ss20); atomicAdd(r0+3,xs0); atomicAdd(r0+4,xs20);
    atomicAdd(r1+0,c1); atomicAdd(r1+1,ss1); atomicAdd(r1+2,ss21); atomicAdd(r1+3,xs1); atomicAdd(r1+4,xs21);
  }
}

__global__ void k_fin_stats(float* ws){
  int i = threadIdx.x;
  if(i<8){
    float* raw = ws + WS_STATS_RAW + i*8;
    float cntf = fmaxf(raw[0], 1.f);
    float ns = cntf * (float)NSEL;
    float s_avg = raw[1]/ns, s_avg2 = raw[2]/ns;
    float x_avg = raw[3]/(ns*3.f), x_avg2 = raw[4]/(ns*3.f);
    float std_s = sqrtf(fmaxf(s_avg2 - s_avg*s_avg, 0.f)) + 1e-8f;
    float std_x = sqrtf(fmaxf(x_avg2 - x_avg*x_avg, 0.f)) + 1e-8f;
    float* fin = ws + WS_STATS_FIN + i*8;
    fin[0]=s_avg; fin[1]=1.f/std_s; fin[2]=1.f/std_x; fin[3]=cntf; fin[4]=raw[0];
  }
}

__global__ void k_index(const int* __restrict__ types, float* __restrict__ ws){
  int b = blockIdx.x;
  int rc0 = (int)ws[WS_STATS_FIN + (b*2)*8 + 4];
  int pad0 = (rc0+63)&~63;
  int* ctr = (int*)ws + WS_CTR;
  int* idx = (int*)ws + WS_IDX;
  for(int n=threadIdx.x;n<NATOM;n+=256){
    int t = types[b*NATOM+n];
    int pos = atomicAdd(&ctr[b*2+t],1);
    idx[b*1152 + (t ? pad0+pos : pos)] = n;
  }
}

// ---- descriptor forward via MFMA filter layers (storeGT path) ----
__global__ void __launch_bounds__(128) k_fwdm(const float* __restrict__ sym, const int* __restrict__ types,
    const float* __restrict__ fw0,const float* __restrict__ fb0,
    const float* __restrict__ fb1,const float* __restrict__ fb2,
    float* __restrict__ ws){
  extern __shared__ char fraw[];
  float* Rn4 = (float*)fraw;                              // 512 f -> 2048
  float* RG4 = (float*)(fraw + 2048);                     // 400 f -> 3648
  float* red = (float*)(fraw + 3648);                     // 8 f  -> 3680
  unsigned short* a2F = (unsigned short*)(fraw + 3680);   // [128][66] -> 20576
  unsigned* a2Fu = (unsigned*)(fraw + 3680);              // stride 33 uints
  unsigned* a1L = (unsigned*)(fraw + 20576);              // [128][17] uints (aliases Gl)
  unsigned short* Gl = (unsigned short*)(fraw + 20576);   // [128][GSTR] ushort -> 48224

  const int bid = blockIdx.x;
  const int b = bid >> 10;
  int t = types[bid];
  t = __builtin_amdgcn_readfirstlane(t);
  const float* fin = ws + WS_STATS_FIN + (b*2+t)*8;
  const float avg_s = fin[0], inv_ss = fin[1], inv_sx = fin[2];
  const int s = threadIdx.x;
  const int wave = s>>6, lane = s&63, lw = lane&15, lg = lane>>4;

  const float* W0 = fw0 + t*H1; const float* B0 = fb0 + t*H1;
  const float* B1 = fb1 + t*H2; const float* B2 = fb2 + t*HM;
  const unsigned* wsu = (const unsigned*)ws;
  const bf16x8* BF1 = (const bf16x8*)(wsu + WS_BF1B) + t*4*64;
  const bf16x8* BF2 = (const bf16x8*)(wsu + WS_BF2B) + t*14*64;

  float4 R4 = *(const float4*)&sym[(size_t)bid*NSEL*4 + s*4];
  float rn0 = (R4.x-avg_s)*inv_ss, rn1 = R4.y*inv_sx, rn2 = R4.z*inv_sx, rn3 = R4.w*inv_sx;
  *(float4*)&Rn4[s*4] = make_float4(rn0,rn1,rn2,rn3);

  {
    float a1r[H1];
#pragma unroll
    for(int kk=0;kk<H1;kk++) a1r[kk] = ftanh(rn0*W0[kk] + B0[kk]);
    unsigned* rw = a1L + s*17;
#pragma unroll
    for(int q=0;q<12;q++) rw[q] = packbf(a1r[2*q], a1r[2*q+1]);
    rw[12] = packbf(a1r[24], 0.f);
    rw[13]=0; rw[14]=0; rw[15]=0; rw[16]=0;
  }
  __syncthreads();

  const f32x4 fz = {0.f,0.f,0.f,0.f};
  for(int nt=0;nt<4;nt++){
    f32x4 acc[4];
#pragma unroll
    for(int mt=0;mt<4;mt++){
      int MT = wave*4 + mt;
      bf16x8 af = *(const bf16x8*)&a1L[(MT*16+lw)*17 + lg*4];
      acc[mt] = __builtin_amdgcn_mfma_f32_16x16x32_bf16(af, BF1[nt*64+lane], fz, 0,0,0);
    }
    int col = nt*16 + lw;
    float bias = (col<H2) ? B1[col] : 0.f;
#pragma unroll
    for(int mt=0;mt<4;mt++)
#pragma unroll
      for(int r=0;r<4;r++){
        int rw = (wave*4+mt)*16 + lg*4 + r;
        float v = (col<H2) ? ftanh(acc[mt][r] + bias) : 0.f;
        a2F[rw*66 + col] = f2bf(v);
      }
  }
  __syncthreads();
  for(int nt=0;nt<7;nt++){
    f32x4 acc[4];
#pragma unroll
    for(int mt=0;mt<4;mt++) acc[mt] = fz;
    for(int ks=0;ks<2;ks++){
#pragma unroll
      for(int mt=0;mt<4;mt++){
        int MT = wave*4 + mt;
        bf16x8 af = *(const bf16x8*)&a2Fu[(MT*16+lw)*33 + ks*16 + lg*4];
        acc[mt] = __builtin_amdgcn_mfma_f32_16x16x32_bf16(af, BF2[(nt*2+ks)*64+lane], acc[mt], 0,0,0);
      }
    }
    int col = nt*16 + lw;
    if(col < HM){
      float bias = B2[col];
#pragma unroll
      for(int mt=0;mt<4;mt++)
#pragma unroll
        for(int r=0;r<4;r++){
          int rw = (wave*4+mt)*16 + lg*4 + r;
          Gl[rw*GSTR + col] = f2bf(ftanh(acc[mt][r] + bias));
        }
    }
  }
  __syncthreads();
  if(s < HM){
    const int m = s;
    float a0=0,b0=0,c0=0,d0=0;
    for(int sn=0;sn<NSEL;sn++){
      float4 rn = *(const float4*)&Rn4[sn*4];
      float g = bf2f(Gl[sn*GSTR+m]);
      a0 += rn.x*g; b0 += rn.y*g; c0 += rn.z*g; d0 += rn.w*g;
    }
    *(float4*)&RG4[m*4] = make_float4(a0,b0,c0,d0);
  }
  __syncthreads();
  for(int i=s;i<HM*4;i+=128) ws[WS_RGB + (size_t)bid*(HM*4) + i] = RG4[i];
  {
    unsigned* GT = (unsigned*)ws + WS_GTB + (size_t)bid*((HM/2)*NSEL);
    for(int i=s;i<(HM/2)*NSEL;i+=128){
      int mp = i >> 7, ss = i & 127;
      GT[i] = *(const unsigned*)&Gl[ss*GSTR + 2*mp];
    }
  }
  float lsum=0,lsum2=0;
  float* gout = ws + WS_G + (size_t)bid*GF;
  for(int i=s;i<GF;i+=128){
    int m=i>>4, a=i&15;
    float4 rm = *(const float4*)&RG4[m*4];
    float4 ra = *(const float4*)&RG4[a*4];
    float gv = rm.x*ra.x + rm.y*ra.y + rm.z*ra.z + rm.w*ra.w;
    gout[i]=gv; lsum+=gv; lsum2+=gv*gv;
  }
  lsum = block_sum2(lsum, red);
  lsum2 = block_sum2(lsum2, red);
  if(s==0){
    atomicAdd(&ws[WS_MUSD_RAW + (b*2+t)*2 + 0], lsum);
    atomicAdd(&ws[WS_MUSD_RAW + (b*2+t)*2 + 1], lsum2);
  }
}

// ---- scalar descriptor forward (fallback) ----
__global__ void __launch_bounds__(128) k_fwd(const float* __restrict__ sym, const int* __restrict__ types,
    const float* __restrict__ fw0,const float* __restrict__ fb0,
    const float* __restrict__ fb1,const float* __restrict__ fb2,
    float* __restrict__ ws){
  __shared__ float Rn4[NSEL*4];
  __shared__ unsigned short Gl[NSEL*GSTR];
  __shared__ float RG4[HM*4];
  __shared__ float red[8];

  const int bid = blockIdx.x;
  const int b = bid >> 10;
  int t = types[bid];
  t = __builtin_amdgcn_readfirstlane(t);
  const float* fin = ws + WS_STATS_FIN + (b*2+t)*8;
  const float avg_s = fin[0], inv_ss = fin[1], inv_sx = fin[2];
  const int s = threadIdx.x;

  const float* W0 = fw0 + t*H1; const float* B0 = fb0 + t*H1;
  const float* B1 = fb1 + t*H2; const float* B2 = fb2 + t*HM;
  const float* W1T = ws + WS_FW1T + t*H2*H1;
  const float* W2T = ws + WS_FW2T + t*HM*H2;

  float4 R4 = *(const float4*)&sym[(size_t)bid*NSEL*4 + s*4];
  float rn0 = (R4.x-avg_s)*inv_ss, rn1 = R4.y*inv_sx, rn2 = R4.z*inv_sx, rn3 = R4.w*inv_sx;
  *(float4*)&Rn4[s*4] = make_float4(rn0,rn1,rn2,rn3);

  float a1[H1];
#pragma unroll
  for(int k=0;k<H1;k++) a1[k] = ftanh(rn0*W0[k] + B0[k]);
  float a2[H2];
#pragma unroll
  for(int j=0;j<H2;j++){
    float acc = B1[j];
    const float* wr = W1T + j*H1;
#pragma unroll
    for(int k=0;k<H1;k++) acc += a1[k]*wr[k];
    a2[j] = ftanh(acc);
  }
  for(int m=0;m<HM;m+=4){
    const float* wr0 = W2T + m*H2; const float* wr1 = wr0 + H2;
    const float* wr2 = wr1 + H2;  const float* wr3 = wr2 + H2;
    float acc0 = B2[m], acc1 = B2[m+1], acc2 = B2[m+2], acc3 = B2[m+3];
#pragma unroll
    for(int j=0;j<H2;j++){
      float aj = a2[j];
      acc0 += aj*wr0[j]; acc1 += aj*wr1[j]; acc2 += aj*wr2[j]; acc3 += aj*wr3[j];
    }
    unsigned u0 = (unsigned)f2bf(ftanh(acc0)) | ((unsigned)f2bf(ftanh(acc1))<<16);
    unsigned u1 = (unsigned)f2bf(ftanh(acc2)) | ((unsigned)f2bf(ftanh(acc3))<<16);
    *(unsigned*)&Gl[s*GSTR + m] = u0;
    *(unsigned*)&Gl[s*GSTR + m + 2] = u1;
  }
  __syncthreads();
  if(s < HM){
    const int m = s;
    float a0=0,b0=0,c0=0,d0=0;
    for(int sn=0;sn<NSEL;sn++){
      float4 rn = *(const float4*)&Rn4[sn*4];
      float g = bf2f(Gl[sn*GSTR+m]);
      a0 += rn.x*g; b0 += rn.y*g; c0 += rn.z*g; d0 += rn.w*g;
    }
    *(float4*)&RG4[m*4] = make_float4(a0,b0,c0,d0);
  }
  __syncthreads();
  for(int i=s;i<HM*4;i+=128) ws[WS_RGB + (size_t)bid*(HM*4) + i] = RG4[i];
  float lsum=0,lsum2=0;
  float* gout = ws + WS_G + (size_t)bid*GF;
  for(int i=s;i<GF;i+=128){
    int m=i>>4, a=i&15;
    float4 rm = *(const float4*)&RG4[m*4];
    float4 ra = *(const float4*)&RG4[a*4];
    float gv = rm.x*ra.x + rm.y*ra.y + rm.z*ra.z + rm.w*ra.w;
    gout[i]=gv; lsum+=gv; lsum2+=gv*gv;
  }
  lsum = block_sum2(lsum, red);
  lsum2 = block_sum2(lsum2, red);
  if(s==0){
    atomicAdd(&ws[WS_MUSD_RAW + (b*2+t)*2 + 0], lsum);
    atomicAdd(&ws[WS_MUSD_RAW + (b*2+t)*2 + 1], lsum2);
  }
}

__global__ void k_fin_musd(float* ws){
  int i=threadIdx.x;
  if(i<8){
    float cntf = ws[WS_STATS_FIN + i*8 + 3];
    float denom = cntf * (float)GF;
    float Sg = ws[WS_MUSD_RAW + i*2], Sg2 = ws[WS_MUSD_RAW + i*2+1];
    float mu = Sg/denom, mu2 = Sg2/denom;
    float var = fmaxf(mu2 - mu*mu, 0.f);
    float r = sqrtf(var); float sd = r + 1e-8f;
    float* mf = ws + WS_MUSD_FIN + i*4;
    mf[0]=mu; mf[1]=1.f/sd; mf[2]=r; mf[3]=sd;
  }
}

// ---- fitting net via MFMA: fwd+bwd through dz1; dz1 image stored for k_pm ----
__global__ void __launch_bounds__(256) k_fitm(
    const float* __restrict__ gb0,const float* __restrict__ gb1,
    const float* __restrict__ gb2,
    const float* __restrict__ gwo,const float* __restrict__ gbo,
    float* __restrict__ ws){
  extern __shared__ unsigned short lb[];
  unsigned short* h1S = lb;              // [64][264]
  unsigned short* h2S = lb + 16896;
  unsigned short* dzA = lb + 33792;

  const int b = blockIdx.x / NGRP64;
  const int grp = blockIdx.x - b*NGRP64;
  int rc0 = (int)ws[WS_STATS_FIN + (b*2)*8 + 4];
  int rc1 = (int)ws[WS_STATS_FIN + (b*2+1)*8 + 4];
  rc0 = __builtin_amdgcn_readfirstlane(rc0);
  rc1 = __builtin_amdgcn_readfirstlane(rc1);
  const int pad0 = (rc0+63)&~63;
  const int tend = pad0 + ((rc1+63)&~63);
  const int slot0 = grp*64;
  if(slot0 >= tend) return;
  const int t = (slot0 >= pad0) ? 1 : 0;

  const float* mf = ws + WS_MUSD_FIN + (b*2+t)*4;
  const float mu = mf[0], isd = mf[1];

  const int tid = threadIdx.x;
  const int wave = tid>>6, lane = tid&63;
  const int lw = lane&15, lg = lane>>4;
  const int mRowBase = wave*16 + lg*4;

  const int* idx = (const int*)ws + WS_IDX + b*1152;
  int arow = idx[slot0 + wave*16 + lw];
  int rowSafe = arow<0?0:arow;
  const float* yrowA = ws + WS_G + (size_t)(b*NATOM + rowSafe)*GF;
  int idC[4];
#pragma unroll
  for(int r=0;r<4;r++) idC[r] = idx[slot0 + wave*16 + lg*4 + r];

  const unsigned* wsu = (const unsigned*)ws;
  const bf16x8* BP0  = (const bf16x8*)(wsu + WS_BP0)  + (size_t)t*15*50*64;
  const bf16x8* BP1  = (const bf16x8*)(wsu + WS_BP1)  + t*15*8*64;
  const bf16x8* BP2  = (const bf16x8*)(wsu + WS_BP2)  + t*15*8*64;
  const bf16x8* BPT2 = (const bf16x8*)(wsu + WS_BPT2) + t*15*8*64;
  const bf16x8* BPT1 = (const bf16x8*)(wsu + WS_BPT1) + t*15*8*64;

  for(int i=tid;i<64*24;i+=256){
    int r = i/24, c = 240 + (i - (i/24)*24);
    h1S[r*264+c]=0; h2S[r*264+c]=0; dzA[r*264+c]=0;
  }

  f32x4 acc[15];
  const f32x4 fz = {0.f,0.f,0.f,0.f};
#pragma unroll
  for(int nt=0;nt<15;nt++) acc[nt] = fz;
  for(int ks=0;ks<50;ks++){
    float4 y0 = *(const float4*)(yrowA + ks*32 + lg*8);
    float4 y1 = *(const float4*)(yrowA + ks*32 + lg*8 + 4);
    union{ unsigned u[4]; bf16x8 v; } A;
    A.u[0]=packbf((y0.x-mu)*isd,(y0.y-mu)*isd); A.u[1]=packbf((y0.z-mu)*isd,(y0.w-mu)*isd);
    A.u[2]=packbf((y1.x-mu)*isd,(y1.y-mu)*isd); A.u[3]=packbf((y1.z-mu)*isd,(y1.w-mu)*isd);
#pragma unroll
    for(int nt=0;nt<15;nt++)
      acc[nt] = __builtin_amdgcn_mfma_f32_16x16x32_bf16(A.v, BP0[(nt*50+ks)*64+lane], acc[nt], 0,0,0);
  }
#pragma unroll
  for(int nt=0;nt<15;nt++){
    float bias = gb0[t*FI + nt*16 + lw];
#pragma unroll
    for(int r=0;r<4;r++){
      float h = ftanh(acc[nt][r] + bias);
      h1S[(mRowBase+r)*264 + nt*16 + lw] = f2bf(h);
    }
  }
  __syncthreads();
#pragma unroll
  for(int nt=0;nt<15;nt++) acc[nt] = fz;
  for(int ks=0;ks<8;ks++){
    bf16x8 a = *(const bf16x8*)&h1S[(wave*16+lw)*264 + ks*32 + lg*8];
#pragma unroll
    for(int nt=0;nt<15;nt++)
      acc[nt] = __builtin_amdgcn_mfma_f32_16x16x32_bf16(a, BP1[(nt*8+ks)*64+lane], acc[nt], 0,0,0);
  }
#pragma unroll
  for(int nt=0;nt<15;nt++){
    float bias = gb1[t*FI + nt*16 + lw];
#pragma unroll
    for(int r=0;r<4;r++){
      float h = ftanh(acc[nt][r] + bias);
      h2S[(mRowBase+r)*264 + nt*16 + lw] = f2bf(h);
    }
  }
  __syncthreads();
#pragma unroll
  for(int nt=0;nt<15;nt++) acc[nt] = fz;
  for(int ks=0;ks<8;ks++){
    bf16x8 a = *(const bf16x8*)&h2S[(wave*16+lw)*264 + ks*32 + lg*8];
#pragma unroll
    for(int nt=0;nt<15;nt++)
      acc[nt] = __builtin_amdgcn_mfma_f32_16x16x32_bf16(a, BP2[(nt*8+ks)*64+lane], acc[nt], 0,0,0);
  }
  float pe[4] = {0.f,0.f,0.f,0.f};
#pragma unroll
  for(int nt=0;nt<15;nt++){
    float bias = gb2[t*FI + nt*16 + lw];
    float wo = gwo[t*FI + nt*16 + lw];
#pragma unroll
    for(int r=0;r<4;r++){
      float h = ftanh(acc[nt][r] + bias);
      pe[r] += h*wo;
      float d3 = wo*(1.f - h*h);
      dzA[(mRowBase+r)*264 + nt*16 + lw] = f2bf(d3);
    }
  }
#pragma unroll
  for(int o=1;o<16;o<<=1){
#pragma unroll
    for(int r=0;r<4;r++) pe[r] += __shfl_xor(pe[r], o, 64);
  }
  if(lw==0){
#pragma unroll
    for(int r=0;r<4;r++) if(idC[r]>=0) ws[WS_EBUF + b*NATOM + idC[r]] = pe[r] + gbo[t];
  }
  __syncthreads();
#pragma unroll
  for(int nt=0;nt<15;nt++) acc[nt] = fz;
  for(int ks=0;ks<8;ks++){
    bf16x8 a = *(const bf16x8*)&dzA[(wave*16+lw)*264 + ks*32 + lg*8];
#pragma unroll
    for(int nt=0;nt<15;nt++)
      acc[nt] = __builtin_amdgcn_mfma_f32_16x16x32_bf16(a, BPT2[(nt*8+ks)*64+lane], acc[nt], 0,0,0);
  }
#pragma unroll
  for(int nt=0;nt<15;nt++){
#pragma unroll
    for(int r=0;r<4;r++){
      float h2 = bf2f(h2S[(mRowBase+r)*264 + nt*16 + lw]);
      acc[nt][r] *= (1.f - h2*h2);
    }
  }
  __syncthreads();
#pragma unroll
  for(int nt=0;nt<15;nt++){
#pragma unroll
    for(int r=0;r<4;r++) dzA[(mRowBase+r)*264 + nt*16 + lw] = f2bf(acc[nt][r]);
  }
  __syncthreads();
#pragma unroll
  for(int nt=0;nt<15;nt++) acc[nt] = fz;
  for(int ks=0;ks<8;ks++){
    bf16x8 a = *(const bf16x8*)&dzA[(wave*16+lw)*264 + ks*32 + lg*8];
#pragma unroll
    for(int nt=0;nt<15;nt++)
      acc[nt] = __builtin_amdgcn_mfma_f32_16x16x32_bf16(a, BPT1[(nt*8+ks)*64+lane], acc[nt], 0,0,0);
  }
#pragma unroll
  for(int nt=0;nt<15;nt++){
#pragma unroll
    for(int r=0;r<4;r++){
      float h1 = bf2f(h1S[(mRowBase+r)*264 + nt*16 + lw]);
      acc[nt][r] *= (1.f - h1*h1);
    }
  }
  __syncthreads();
#pragma unroll
  for(int nt=0;nt<15;nt++){
#pragma unroll
    for(int r=0;r<4;r++) dzA[(mRowBase+r)*264 + nt*16 + lw] = f2bf(acc[nt][r]);
  }
  __syncthreads();
  // store dz1 frag image for k_pm
  {
    unsigned* dzOut = (unsigned*)ws + WS_DZ1 + (size_t)blockIdx.x*8448;
    const unsigned* dzAu = (const unsigned*)dzA;
    for(int i=tid;i<8448;i+=256) dzOut[i] = dzAu[i];
  }
}

// ---- p = dz1 @ gw0^T, N-chunked across blocks (all-CU coverage) + S1/Sy ----
__global__ void __launch_bounds__(256) k_pm(float* __restrict__ ws){
  extern __shared__ unsigned short lb[];   // dzA image [64][264]
  unsigned short* dzA = lb;
  __shared__ float red[4];

  const int gid = blockIdx.x / PCH;
  const int chunk = blockIdx.x - gid*PCH;
  const int b = gid / NGRP64;
  const int grp = gid - b*NGRP64;
  int rc0 = (int)ws[WS_STATS_FIN + (b*2)*8 + 4];
  int rc1 = (int)ws[WS_STATS_FIN + (b*2+1)*8 + 4];
  rc0 = __builtin_amdgcn_readfirstlane(rc0);
  rc1 = __builtin_amdgcn_readfirstlane(rc1);
  const int pad0 = (rc0+63)&~63;
  const int tend = pad0 + ((rc1+63)&~63);
  const int slot0 = grp*64;
  if(slot0 >= tend) return;
  const int t = (slot0 >= pad0) ? 1 : 0;

  const float* mf = ws + WS_MUSD_FIN + (b*2+t)*4;
  const float mu = mf[0], isd = mf[1];
  const int tid = threadIdx.x;
  const int wave = tid>>6, lane = tid&63, lw = lane&15, lg = lane>>4;

  const int* idx = (const int*)ws + WS_IDX + b*1152;
  int idC[4];
#pragma unroll
  for(int r=0;r<4;r++) idC[r] = idx[slot0 + wave*16 + lg*4 + r];

  const unsigned* wsu = (const unsigned*)ws;
  const bf16x8* BPT0 = (const bf16x8*)(wsu + WS_BPT0) + (size_t)t*100*8*64;

  // load dz1 image
  {
    const unsigned* src = (const unsigned*)ws + WS_DZ1 + (size_t)gid*8448;
    unsigned* dst = (unsigned*)lb;
    for(int i=tid;i<8448;i+=256) dst[i] = src[i];
  }
  __syncthreads();

  const f32x4 fz = {0.f,0.f,0.f,0.f};
  const float* yG = ws + WS_G + (size_t)b*NATOM*GF;
  float* pP = ws + WS_P + (size_t)b*NATOM*GF;
  float s1t=0.f, syt=0.f;
  for(int sc=0;sc<2;sc++){
    int c0 = chunk*20 + sc*10;
    f32x4 pc[10];
#pragma unroll
    for(int j=0;j<10;j++) pc[j] = fz;
    for(int ks=0;ks<8;ks++){
      bf16x8 a = *(const bf16x8*)&dzA[(wave*16+lw)*264 + ks*32 + lg*8];
#pragma unroll
      for(int j=0;j<10;j++)
        pc[j] = __builtin_amdgcn_mfma_f32_16x16x32_bf16(a, BPT0[((c0+j)*8+ks)*64+lane], pc[j], 0,0,0);
    }
#pragma unroll
    for(int j=0;j<10;j++){
      int n = (c0+j)*16 + lw;
#pragma unroll
      for(int r=0;r<4;r++){
        if(idC[r]>=0){
          float pv = pc[j][r];
          size_t off = (size_t)idC[r]*GF + n;
          pP[off] = pv;
          s1t += pv;
          syt += pv * (yG[off]-mu)*isd;
        }
      }
    }
  }
  s1t = block_sum4(s1t, red);
  syt = block_sum4(syt, red);
  if(tid==0){
    atomicAdd(&ws[WS_S_RAW+(b*2+t)*2+0], s1t);
    atomicAdd(&ws[WS_S_RAW+(b*2+t)*2+1], syt);
  }
}

// ---- descriptor backward via MFMA, compact LDS: 1 atom/block, 128 thr (r19 proven)
//      + phase-D GT batch-prefetch into registers (r21) ----
__global__ void __launch_bounds__(128) k_bwdm2(const float* __restrict__ sym,
    const float* __restrict__ dxp,const float* __restrict__ dyp,const float* __restrict__ dzp,
    const int* __restrict__ types,
    const float* __restrict__ fw0,const float* __restrict__ fb0,
    const float* __restrict__ fb1,
    float* __restrict__ ws, float* __restrict__ out){
  extern __shared__ char lraw[];
  float* dRG4 = (float*)lraw;
  float* red  = (float*)(lraw + 1600);
  float* dgb  = (float*)(lraw + 1664);
  float* RG4  = (float*)(lraw + 8464);
  unsigned short* a2L = (unsigned short*)(lraw + 1664);    // stride 51
  unsigned* dz2u = (unsigned*)(lraw + 14720);              // stride 25
  unsigned short* dz2s = (unsigned short*)(lraw + 14720);  // stride 50
  unsigned* ML = (unsigned*)(lraw + 27648);                // stride 51
  unsigned short* dz1L = (unsigned short*)(lraw + 27648);  // stride 28

  const int bid = blockIdx.x;
  const int b = bid >> 10;
  int t = types[bid];
  t = __builtin_amdgcn_readfirstlane(t);
  const float* fin = ws + WS_STATS_FIN + (b*2+t)*8;
  const float avg_s=fin[0], inv_ss=fin[1], inv_sx=fin[2], cntf=fin[3];
  const float* mf = ws + WS_MUSD_FIN + (b*2+t)*4;
  const float mu=mf[0], inv_sd=mf[1], rr=mf[2];
  const float S1 = ws[WS_S_RAW + (b*2+t)*2 + 0];
  const float Sy = ws[WS_S_RAW + (b*2+t)*2 + 1];
  const float denom = cntf * (float)GF;
  const float c1 = S1/denom;
  const float c2 = (rr>0.f) ? (Sy/denom)/rr : 0.f;
  const int s = threadIdx.x;
  const int wave = s>>6, lane = s&63, lw = lane&15, lg = lane>>4;

  const float* W0 = fw0 + t*H1; const float* B0 = fb0 + t*H1;
  const float* B1f = fb1 + t*H2;
  const unsigned* wsu = (const unsigned*)ws;
  const bf16x8* BF1  = (const bf16x8*)(wsu + WS_BF1B)  + t*4*64;
  const bf16x8* BW2T = (const bf16x8*)(wsu + WS_BW2TB) + t*16*64;
  const bf16x8* BW1T = (const bf16x8*)(wsu + WS_BW1TB) + t*4*64;

  if(s < 32) ((unsigned*)(lraw + 14720))[128*25 + s] = 0;
  if(s < 64) ML[128*51 + s] = 0;

  for(int i=s;i<HM*4;i+=128) RG4[i] = ws[WS_RGB + (size_t)bid*(HM*4) + i];
  __syncthreads();
  const float* p = ws + WS_P + (size_t)bid*GF;
  for(int i=s;i<GF;i+=128){
    int m=i>>4, a=i&15;
    float4 rm = *(const float4*)&RG4[m*4];
    float4 ra = *(const float4*)&RG4[a*4];
    float gv = rm.x*ra.x + rm.y*ra.y + rm.z*ra.z + rm.w*ra.w;
    float yv = (gv-mu)*inv_sd;
    dgb[m*17+a] = (p[i]-c1)*inv_sd - yv*c2;
  }
  __syncthreads();
  if(s < HM){
    const int m = s;
    float a0=0,b0=0,c0=0,d0=0;
#pragma unroll
    for(int a=0;a<AX;a++){
      float d = dgb[m*17+a];
      float4 r = *(const float4*)&RG4[a*4];
      a0 += d*r.x; b0 += d*r.y; c0 += d*r.z; d0 += d*r.w;
    }
    if(m<AX){
      for(int mp=0;mp<HM;mp++){
        float d = dgb[mp*17+m];
        float4 r = *(const float4*)&RG4[mp*4];
        a0 += d*r.x; b0 += d*r.y; c0 += d*r.z; d0 += d*r.w;
      }
    }
    *(float4*)&dRG4[m*4] = make_float4(a0,b0,c0,d0);
  }
  float4 R4 = *(const float4*)&sym[(size_t)bid*NSEL*4 + s*4];
  float rn0 = (R4.x-avg_s)*inv_ss, rn1 = R4.y*inv_sx, rn2 = R4.z*inv_sx, rn3 = R4.w*inv_sx;
  {
    float a1r[H1];
#pragma unroll
    for(int kk=0;kk<H1;kk++) a1r[kk] = ftanh(rn0*W0[kk] + B0[kk]);
    unsigned* row = ML + s*51;
#pragma unroll
    for(int q=0;q<12;q++) row[q] = packbf(a1r[2*q], a1r[2*q+1]);
    row[12] = packbf(a1r[24], 0.f);
    row[13]=0; row[14]=0; row[15]=0; row[16]=0;
  }
  __syncthreads();

  const f32x4 fz = {0.f,0.f,0.f,0.f};
  // ---- C: a2 = tanh(a1 @ fw1 + b1) -> a2L (cols < 50 only)
  for(int nt=0;nt<4;nt++){
    f32x4 acc[4];
#pragma unroll
    for(int mt=0;mt<4;mt++){
      bf16x8 af = *(const bf16x8*)&ML[((wave*4+mt)*16+lw)*51 + lg*4];
      acc[mt] = __builtin_amdgcn_mfma_f32_16x16x32_bf16(af, BF1[nt*64+lane], fz, 0,0,0);
    }
    int col = nt*16 + lw;
    if(col < H2){
      float bias = B1f[col];
#pragma unroll
      for(int mt=0;mt<4;mt++)
#pragma unroll
        for(int r=0;r<4;r++){
          int rw = (wave*4+mt)*16 + lg*4 + r;
          a2L[rw*51 + col] = f2bf(ftanh(acc[mt][r] + bias));
        }
    }
  }
  __syncthreads();
  // ---- D: dz3 -> ML rows; fused drn. All 50 GT loads issued up-front into
  //      registers (fully unrolled, static indices -> no scratch) so the
  //      ~50 serial L2/HBM latencies collapse to ~1.
  const unsigned* GT = (const unsigned*)ws + WS_GTB + (size_t)bid*((HM/2)*NSEL);
  float drn0=0,drn1=0,drn2=0,drn3=0;
  {
    unsigned uv[50];
#pragma unroll
    for(int q=0;q<50;q++) uv[q] = GT[q*NSEL + s];
    unsigned* row = ML + s*51;
#pragma unroll
    for(int q=0;q<50;q++){
      int m0 = 2*q;
      unsigned u = uv[q];
      float g0 = bflo(u), g1 = bfhi(u);
      float4 dm0 = *(const float4*)&dRG4[m0*4];
      float4 dm1 = *(const float4*)&dRG4[(m0+1)*4];
      drn0 += dm0.x*g0 + dm1.x*g1;
      drn1 += dm0.y*g0 + dm1.y*g1;
      drn2 += dm0.z*g0 + dm1.z*g1;
      drn3 += dm0.w*g0 + dm1.w*g1;
      float d30 = (dm0.x*rn0 + dm0.y*rn1 + dm0.z*rn2 + dm0.w*rn3)*(1.f-g0*g0);
      float d31 = (dm1.x*rn0 + dm1.y*rn1 + dm1.z*rn2 + dm1.w*rn3)*(1.f-g1*g1);
      row[q] = packbf(d30, d31);
    }
    row[50] = 0;
  }
  __syncthreads();
  // ---- E: dz2 = dz3 @ fw2^T, deriv vs a2L -> dz2s (cols < 50)
  for(int nt=0;nt<4;nt++){
    f32x4 acc[4];
#pragma unroll
    for(int mt=0;mt<4;mt++) acc[mt] = fz;
    for(int ks=0;ks<4;ks++){
#pragma unroll
      for(int mt=0;mt<4;mt++){
        bf16x8 af = *(const bf16x8*)&ML[((wave*4+mt)*16+lw)*51 + ks*16 + lg*4];
        acc[mt] = __builtin_amdgcn_mfma_f32_16x16x32_bf16(af, BW2T[(nt*4+ks)*64+lane], acc[mt], 0,0,0);
      }
    }
    int col = nt*16 + lw;
    if(col < H2){
#pragma unroll
      for(int mt=0;mt<4;mt++)
#pragma unroll
        for(int r=0;r<4;r++){
          int rw = (wave*4+mt)*16 + lg*4 + r;
          float a2v = bf2f(a2L[rw*51 + col]);
          dz2s[rw*50 + col] = f2bf(acc[mt][r]*(1.f - a2v*a2v));
        }
    }
  }
  __syncthreads();
  // ---- F: dz1 = dz2 @ fw1^T -> dz1L (aliases ML)
  for(int nt2=0;nt2<2;nt2++){
    f32x4 acc[4];
#pragma unroll
    for(int mt=0;mt<4;mt++) acc[mt] = fz;
    for(int ks2=0;ks2<2;ks2++){
#pragma unroll
      for(int mt=0;mt<4;mt++){
        bf16x8 af = *(const bf16x8*)&dz2u[((wave*4+mt)*16+lw)*25 + ks2*16 + lg*4];
        acc[mt] = __builtin_amdgcn_mfma_f32_16x16x32_bf16(af, BW1T[(nt2*2+ks2)*64+lane], acc[mt], 0,0,0);
      }
    }
    int col = nt2*16 + lw;
    if(col < 28){
#pragma unroll
      for(int mt=0;mt<4;mt++)
#pragma unroll
        for(int r=0;r<4;r++){
          int rw = (wave*4+mt)*16 + lg*4 + r;
          dz1L[rw*28 + col] = f2bf((col<H1) ? acc[mt][r] : 0.f);
        }
    }
  }
  __syncthreads();
  // ---- G: ds per row (a1 recomputed from rn0)
  {
    float ds = 0.f;
#pragma unroll
    for(int kk=0;kk<H1;kk++){
      float w0v = W0[kk];
      float a1v = ftanh(rn0*w0v + B0[kk]);
      float d1 = bf2f(dz1L[s*28 + kk]);
      ds += d1*(1.f - a1v*a1v)*w0v;
    }
    drn0 += ds;
  }
  // ---- H: forces
  float w0 = drn0*inv_ss, w1 = drn1*inv_sx, w2 = drn2*inv_sx, w3 = drn3*inv_sx;
  float4 X = *(const float4*)&dxp[(size_t)bid*NSEL*4 + s*4];
  float4 Y = *(const float4*)&dyp[(size_t)bid*NSEL*4 + s*4];
  float4 Z = *(const float4*)&dzp[(size_t)bid*NSEL*4 + s*4];
  float fx = w0*X.x + w1*X.y + w2*X.z + w3*X.w;
  float fy = w0*Y.x + w1*Y.y + w2*Y.z + w3*Y.w;
  float fz2 = w0*Z.x + w1*Z.y + w2*Z.z + w3*Z.w;
  fx = wave_sum(fx); fy = wave_sum(fy); fz2 = wave_sum(fz2);
  __syncthreads();
  if((s&63)==0){ int w=s>>6; red[w*3+0]=fx; red[w*3+1]=fy; red[w*3+2]=fz2; }
  __syncthreads();
  if(s==0){
    float* F = out + 4 + (size_t)bid*3;
    F[0] = -(red[0]+red[3]);
    F[1] = -(red[1]+red[4]);
    F[2] = -(red[2]+red[5]);
  }
}

// ---- scalar fallback backward (recompute G) ----
__global__ void __launch_bounds__(128) k_bwd0(const float* __restrict__ sym,
    const float* __restrict__ dxp,const float* __restrict__ dyp,const float* __restrict__ dzp,
    const int* __restrict__ types,
    const float* __restrict__ fw0,const float* __restrict__ fb0,
    const float* __restrict__ fw1,const float* __restrict__ fb1,
    const float* __restrict__ fb2,
    float* __restrict__ ws, float* __restrict__ out){
  __shared__ float RG4[HM*4];
  __shared__ float dgb[HM*17];
  __shared__ float dRG4[HM*4];
  __shared__ float red[8];

  const int bid = blockIdx.x;
  const int b = bid >> 10;
  int t = types[bid];
  t = __builtin_amdgcn_readfirstlane(t);
  const float* fin = ws + WS_STATS_FIN + (b*2+t)*8;
  const float avg_s=fin[0], inv_ss=fin[1], inv_sx=fin[2], cntf=fin[3];
  const float* mf = ws + WS_MUSD_FIN + (b*2+t)*4;
  const float mu=mf[0], inv_sd=mf[1], rr=mf[2];
  const float S1 = ws[WS_S_RAW + (b*2+t)*2 + 0];
  const float Sy = ws[WS_S_RAW + (b*2+t)*2 + 1];
  const float denom = cntf * (float)GF;
  const float c1 = S1/denom;
  const float c2 = (rr>0.f) ? (Sy/denom)/rr : 0.f;
  const int s = threadIdx.x;

  const float* W0 = fw0 + t*H1; const float* B0 = fb0 + t*H1;
  const float* B1 = fb1 + t*H2; const float* B2 = fb2 + t*HM;
  const float* W1  = fw1 + t*H1*H2;
  const float* W1T = ws + WS_FW1T + t*H2*H1;
  const float* W2T = ws + WS_FW2T + t*HM*H2;

  for(int i=s;i<HM*4;i+=128) RG4[i] = ws[WS_RGB + (size_t)bid*(HM*4) + i];
  __syncthreads();

  const float* p = ws + WS_P + (size_t)bid*GF;
  for(int i=s;i<GF;i+=128){
    int m=i>>4, a=i&15;
    float4 rm = *(const float4*)&RG4[m*4];
    float4 ra = *(const float4*)&RG4[a*4];
    float gv = rm.x*ra.x + rm.y*ra.y + rm.z*ra.z + rm.w*ra.w;
    float yv = (gv-mu)*inv_sd;
    dgb[m*17+a] = (p[i]-c1)*inv_sd - yv*c2;
  }
  __syncthreads();
  if(s < HM){
    const int m = s;
    float a0=0,b0=0,c0=0,d0=0;
#pragma unroll
    for(int a=0;a<AX;a++){
      float d = dgb[m*17+a];
      float4 r = *(const float4*)&RG4[a*4];
      a0 += d*r.x; b0 += d*r.y; c0 += d*r.z; d0 += d*r.w;
    }
    if(m<AX){
      for(int mp=0;mp<HM;mp++){
        float d = dgb[mp*17+m];
        float4 r = *(const float4*)&RG4[mp*4];
        a0 += d*r.x; b0 += d*r.y; c0 += d*r.z; d0 += d*r.w;
      }
    }
    *(float4*)&dRG4[m*4] = make_float4(a0,b0,c0,d0);
  }
  __syncthreads();

  float4 R4 = *(const float4*)&sym[(size_t)bid*NSEL*4 + s*4];
  float rn0 = (R4.x-avg_s)*inv_ss, rn1 = R4.y*inv_sx, rn2 = R4.z*inv_sx, rn3 = R4.w*inv_sx;

  float a1[H1];
#pragma unroll
  for(int kk=0;kk<H1;kk++) a1[kk] = ftanh(rn0*W0[kk] + B0[kk]);
  float a2[H2];
#pragma unroll
  for(int j=0;j<H2;j++){
    float acc = B1[j];
    const float* wr = W1T + j*H1;
#pragma unroll
    for(int kk=0;kk<H1;kk++) acc += a1[kk]*wr[kk];
    a2[j] = ftanh(acc);
  }

  float dz2a[H2];
#pragma unroll
  for(int j=0;j<H2;j++) dz2a[j]=0.f;
  float drn0=0,drn1=0,drn2=0,drn3=0;
  for(int m=0;m<HM;m+=4){
    const float* wr0 = W2T + m*H2; const float* wr1 = wr0 + H2;
    const float* wr2 = wr1 + H2;  const float* wr3 = wr2 + H2;
    float acc0 = B2[m], acc1 = B2[m+1], acc2 = B2[m+2], acc3 = B2[m+3];
#pragma unroll
    for(int j=0;j<H2;j++){
      float aj = a2[j];
      acc0 += aj*wr0[j]; acc1 += aj*wr1[j]; acc2 += aj*wr2[j]; acc3 += aj*wr3[j];
    }
    float g0 = ftanh(acc0), g1 = ftanh(acc1), g2 = ftanh(acc2), g3 = ftanh(acc3);
    float4 d0 = *(const float4*)&dRG4[m*4];
    float4 d1 = *(const float4*)&dRG4[(m+1)*4];
    float4 d2 = *(const float4*)&dRG4[(m+2)*4];
    float4 d3 = *(const float4*)&dRG4[(m+3)*4];
    drn0 += d0.x*g0 + d1.x*g1 + d2.x*g2 + d3.x*g3;
    drn1 += d0.y*g0 + d1.y*g1 + d2.y*g2 + d3.y*g3;
    drn2 += d0.z*g0 + d1.z*g1 + d2.z*g2 + d3.z*g3;
    drn3 += d0.w*g0 + d1.w*g1 + d2.w*g2 + d3.w*g3;
    float dz30 = (d0.x*rn0 + d0.y*rn1 + d0.z*rn2 + d0.w*rn3)*(1.f-g0*g0);
    float dz31 = (d1.x*rn0 + d1.y*rn1 + d1.z*rn2 + d1.w*rn3)*(1.f-g1*g1);
    float dz32 = (d2.x*rn0 + d2.y*rn1 + d2.z*rn2 + d2.w*rn3)*(1.f-g2*g2);
    float dz33 = (d3.x*rn0 + d3.y*rn1 + d3.z*rn2 + d3.w*rn3)*(1.f-g3*g3);
#pragma unroll
    for(int j=0;j<H2;j++) dz2a[j] += dz30*wr0[j] + dz31*wr1[j] + dz32*wr2[j] + dz33*wr3[j];
  }
#pragma unroll
  for(int j=0;j<H2;j++){ float av=a2[j]; dz2a[j] *= (1.f-av*av); }
  float dsacc=0.f;
#pragma unroll
  for(int kk=0;kk<H1;kk++){
    const float* wr = W1 + kk*H2;
    float acc=0.f;
#pragma unroll
    for(int j=0;j<H2;j++) acc += dz2a[j]*wr[j];
    float av=a1[kk];
    dsacc += acc*(1.f-av*av)*W0[kk];
  }
  drn0 += dsacc;
  float w0 = drn0*inv_ss, w1 = drn1*inv_sx, w2 = drn2*inv_sx, w3 = drn3*inv_sx;
  float4 X = *(const float4*)&dxp[(size_t)bid*NSEL*4 + s*4];
  float4 Y = *(const float4*)&dyp[(size_t)bid*NSEL*4 + s*4];
  float4 Z = *(const float4*)&dzp[(size_t)bid*NSEL*4 + s*4];
  float fx = w0*X.x + w1*X.y + w2*X.z + w3*X.w;
  float fy = w0*Y.x + w1*Y.y + w2*Y.z + w3*Y.w;
  float fz = w0*Z.x + w1*Z.y + w2*Z.z + w3*Z.w;
  fx = wave_sum(fx); fy = wave_sum(fy); fz = wave_sum(fz);
  __syncthreads();
  if((s&63)==0){ int w=s>>6; red[w*3+0]=fx; red[w*3+1]=fy; red[w*3+2]=fz; }
  __syncthreads();
  if(s==0){
    float* F = out + 4 + (size_t)bid*3;
    F[0] = -(red[0]+red[3]);
    F[1] = -(red[1]+red[4]);
    F[2] = -(red[2]+red[5]);
  }
}

__global__ void k_write_E(const float* __restrict__ ws, float* __restrict__ out){
  __shared__ float red[8];
  const int b = blockIdx.x;
  const float* e = ws + WS_EBUF + b*NATOM;
  float sv=0;
  for(int i=threadIdx.x;i<NATOM;i+=256) sv+=e[i];
  sv = block_sum4(sv, red);
  if(threadIdx.x==0) out[b]=sv;
}

extern "C" void kernel_launch(void* const* d_in, const int* in_sizes, int n_in,
                              void* d_out, int out_size, void* d_ws, size_t ws_size,
                              hipStream_t stream) {
  const float* sym = (const float*)d_in[0];
  const float* dxp = (const float*)d_in[1];
  const float* dyp = (const float*)d_in[2];
  const float* dzp = (const float*)d_in[3];
  const int*   types=(const int*)d_in[4];
  const float* fw0=(const float*)d_in[5];
  const float* fb0=(const float*)d_in[6];
  const float* fw1=(const float*)d_in[7];
  const float* fb1=(const float*)d_in[8];
  const float* fw2=(const float*)d_in[9];
  const float* fb2=(const float*)d_in[10];
  const float* gw0=(const float*)d_in[11];
  const float* gb0=(const float*)d_in[12];
  const float* gw1=(const float*)d_in[13];
  const float* gb1=(const float*)d_in[14];
  const float* gw2=(const float*)d_in[15];
  const float* gb2=(const float*)d_in[16];
  const float* gwo=(const float*)d_in[17];
  const float* gbo=(const float*)d_in[18];
  float* ws = (float*)d_ws;
  float* out = (float*)d_out;

  const size_t need_bytes = (size_t)WS_END * 4;
  const int storeGT = (ws_size >= need_bytes) ? 1 : 0;

  hipMemsetAsync(d_ws, 0, 1024, stream);
  hipMemsetAsync((char*)d_ws + (size_t)WS_IDX*4, 0xFF, (size_t)NBATCH*1152*4, stream);

  k_transpose<<<1024,256,0,stream>>>(gw0,gw1,gw2,fw1,fw2,ws);
  if(storeGT) k_packf<<<64,256,0,stream>>>(fw1,fw2,ws);
  k_stats<<<dim3(16,NBATCH),256,0,stream>>>(sym,types,ws);
  k_fin_stats<<<1,64,0,stream>>>(ws);
  k_index<<<NBATCH,256,0,stream>>>(types,ws);

  if(storeGT){
    const int lds_fwdm = 48224;
    hipFuncSetAttribute((const void*)k_fwdm, hipFuncAttributeMaxDynamicSharedMemorySize, lds_fwdm);
    k_fwdm<<<NBATCH*NATOM,128,lds_fwdm,stream>>>(sym,types,fw0,fb0,fb1,fb2,ws);
  } else {
    k_fwd<<<NBATCH*NATOM,128,0,stream>>>(sym,types,fw0,fb0,fb1,fb2,ws);
  }
  k_fin_musd<<<1,64,0,stream>>>(ws);

  const int lds_fitm = 3*64*264*2;   // 101376 B
  hipFuncSetAttribute((const void*)k_fitm, hipFuncAttributeMaxDynamicSharedMemorySize, lds_fitm);
  k_fitm<<<NBATCH*NGRP64,256,lds_fitm,stream>>>(gb0,gb1,gb2,gwo,gbo,ws);

  const int lds_pm = 64*264*2;       // 33792 B
  hipFuncSetAttribute((const void*)k_pm, hipFuncAttributeMaxDynamicSharedMemorySize, lds_pm);
  k_pm<<<NBATCH*NGRP64*PCH,256,lds_pm,stream>>>(ws);

  if(storeGT){
    const int lds_bwdm = 54016;
    hipFuncSetAttribute((const void*)k_bwdm2, hipFuncAttributeMaxDynamicSharedMemorySize, lds_bwdm);
    k_bwdm2<<<NBATCH*NATOM,128,lds_bwdm,stream>>>(sym,dxp,dyp,dzp,types,fw0,fb0,fb1,ws,out);
  } else {
    k_bwd0<<<NBATCH*NATOM,128,0,stream>>>(sym,dxp,dyp,dzp,types,fw0,fb0,fw1,fb1,fb2,ws,out);
  }

  k_write_E<<<NBATCH,256,0,stream>>>(ws,out);
}

// Round 22
// 742.493 us; speedup vs baseline: 1.0697x; 1.0697x over previous
//
#include <hip/hip_runtime.h>

#define NBATCH 4
#define NATOM 1024
#define NSEL 128
#define H1 25
#define H2 50
#define HM 100
#define AX 16
#define GF 1600
#define FI 240
#define NT 2
#define NGRP64 18   // 64-atom type-pure groups per batch (1152/64)
#define PCH 5       // N-chunks for k_pm (20 ntiles each)

// ---- workspace layout (float/uint offsets) ----
#define WS_STATS_RAW 0
#define WS_STATS_FIN 64      // [avg_s, inv_ss, inv_sx, cntf, rawcnt]
#define WS_MUSD_RAW 128
#define WS_MUSD_FIN 144
#define WS_S_RAW 176
#define WS_CTR 192
#define WS_EBUF 256
#define WS_IDX (WS_EBUF + NBATCH*NATOM)                  // ints, per-batch type-sorted, 1152/batch
#define WS_G (WS_IDX + NBATCH*1152)
#define WS_P (WS_G + (size_t)NBATCH*NATOM*GF)
// MFMA B-fragment packs for fit net:
#define WS_BP0  (WS_P + (size_t)NBATCH*NATOM*GF)         // [t][15][50][64][4]  L0 (gw0)
#define WS_BP1  (WS_BP0 + (size_t)NT*15*50*256)          // [t][15][8][64][4]   L1 (gw1)
#define WS_BP2  (WS_BP1 + (size_t)NT*15*8*256)           // L2 (gw2)
#define WS_BPT2 (WS_BP2 + (size_t)NT*15*8*256)           // dz2 (gw2^T)
#define WS_BPT1 (WS_BPT2 + (size_t)NT*15*8*256)          // dz1 (gw1^T)
#define WS_BPT0 (WS_BPT1 + (size_t)NT*15*8*256)          // [t][100][8][64][4]  p (gw0^T)
#define WS_FW1T (WS_BPT0 + (size_t)NT*100*8*256)         // fp32 filter transposes
#define WS_FW2T (WS_FW1T + (size_t)NT*H2*H1)
#define WS_RGB (WS_FW2T + (size_t)NT*HM*H2)              // RG store: NBATCH*NATOM*400
#define WS_GTB (WS_RGB + (size_t)NBATCH*NATOM*HM*4)      // GT-packed bf16 G: [atom][HM/2][NSEL]
#define WS_GTB_UNITS ((size_t)NBATCH*NATOM*(HM/2)*NSEL)
// filter-net B-frag packs:
#define WS_BF1B  (WS_GTB + WS_GTB_UNITS)                 // [t][4nt][64][4]      a2 fwd (fw1)
#define WS_BW2TB (WS_BF1B + (size_t)NT*1024)             // [t][4nt][4ks][64][4] dz2 (fw2^T)
#define WS_BW1TB (WS_BW2TB + (size_t)NT*4096)            // [t][2nt][2ks][64][4] dz1 (fw1^T)
#define WS_BF2B  (WS_BW1TB + (size_t)NT*1024)            // [t][7nt][2ks][64][4] G fwd (fw2)
#define WS_DZ1  (WS_BF2B + (size_t)NT*3584)              // dz1 frag images: [72 groups][8448 uints]
#define WS_END  (WS_DZ1 + (size_t)NBATCH*NGRP64*8448)

#define GSTR 108   // ushort stride for G in LDS

typedef __attribute__((ext_vector_type(8))) short bf16x8;
typedef __attribute__((ext_vector_type(4))) float f32x4;
typedef __attribute__((address_space(1))) const unsigned GU;
typedef __attribute__((address_space(3))) unsigned LU;

__device__ __forceinline__ float ftanh(float x){
  float e = __expf(2.0f*x);
  return 1.0f - 2.0f/(e+1.0f);
}
__device__ __forceinline__ unsigned short f2bf(float x){
  unsigned b=__float_as_uint(x); b += 0x7FFF + ((b>>16)&1); return (unsigned short)(b>>16);
}
__device__ __forceinline__ float bf2f(unsigned short h){ return __uint_as_float(((unsigned)h)<<16); }
__device__ __forceinline__ float bflo(unsigned u){ return __uint_as_float(u<<16); }
__device__ __forceinline__ float bfhi(unsigned u){ return __uint_as_float(u & 0xFFFF0000u); }
__device__ __forceinline__ unsigned packbf(float a, float b){
  return (unsigned)f2bf(a) | ((unsigned)f2bf(b)<<16);
}

__device__ __forceinline__ float wave_sum(float v){
#pragma unroll
  for(int o=32;o>0;o>>=1) v += __shfl_down(v,o,64);
  return v;
}
__device__ __forceinline__ float block_sum2(float v, float* red){
  v = wave_sum(v);
  __syncthreads();
  if((threadIdx.x&63)==0) red[threadIdx.x>>6]=v;
  __syncthreads();
  return red[0]+red[1];
}
__device__ __forceinline__ float block_sum4(float v, float* red){
  v = wave_sum(v);
  __syncthreads();
  if((threadIdx.x&63)==0) red[threadIdx.x>>6]=v;
  __syncthreads();
  return red[0]+red[1]+red[2]+red[3];
}

// ---- pack fit-net MFMA B-fragments (bf16) + fp32 filter transposes ----
__global__ void __launch_bounds__(256) k_transpose(const float* __restrict__ gw0,
    const float* __restrict__ gw1, const float* __restrict__ gw2,
    const float* __restrict__ fw1, const float* __restrict__ fw2, float* __restrict__ ws){
  const int cB0 = NT*15*50*256;
  const int cB1 = NT*15*8*256;
  const int cT0 = NT*100*8*256;
  const int c6 = NT*H2*H1, c7 = NT*HM*H2;
  const int total = cB0 + 4*cB1 + cT0 + c6 + c7;
  unsigned* wsu = (unsigned*)ws;
  for(int i = blockIdx.x*blockDim.x + threadIdx.x; i < total; i += gridDim.x*blockDim.x){
    if(i < cB0 + 4*cB1 + cT0){
      int base, NKs; const float* W; int KK; int mode; int t;
      int ii = i;
      if(ii < cB0){ base=WS_BP0; NKs=50; KK=1600; mode=0; t = ii/(15*50*256); ii -= t*(15*50*256); W = gw0 + (size_t)t*GF*FI; }
      else if(ii < cB0+cB1){ ii-=cB0; base=WS_BP1; NKs=8; KK=240; mode=0; t = ii/(15*8*256); ii -= t*(15*8*256); W = gw1 + t*FI*FI; }
      else if(ii < cB0+2*cB1){ ii-=cB0+cB1; base=WS_BP2; NKs=8; KK=240; mode=0; t = ii/(15*8*256); ii -= t*(15*8*256); W = gw2 + t*FI*FI; }
      else if(ii < cB0+3*cB1){ ii-=cB0+2*cB1; base=WS_BPT2; NKs=8; KK=240; mode=1; t = ii/(15*8*256); ii -= t*(15*8*256); W = gw2 + t*FI*FI; }
      else if(ii < cB0+4*cB1){ ii-=cB0+3*cB1; base=WS_BPT1; NKs=8; KK=240; mode=1; t = ii/(15*8*256); ii -= t*(15*8*256); W = gw1 + t*FI*FI; }
      else { ii-=cB0+4*cB1; base=WS_BPT0; NKs=8; KK=240; mode=2; t = ii/(100*8*256); ii -= t*(100*8*256); W = gw0 + (size_t)t*GF*FI; }
      int d = ii & 3;
      int lane = (ii>>2) & 63;
      int rem = ii >> 8;
      int ks = rem % NKs;
      int ntile = rem / NKs;
      int n = ntile*16 + (lane&15);
      int k0 = ks*32 + ((lane>>4)&3)*8 + 2*d;
      float v0, v1;
      if(mode==0){
        v0 = (k0   < KK) ? W[(size_t)(k0  )*FI + n] : 0.f;
        v1 = (k0+1 < KK) ? W[(size_t)(k0+1)*FI + n] : 0.f;
      } else if(mode==1){
        v0 = (k0   < KK) ? W[n*FI + k0  ] : 0.f;
        v1 = (k0+1 < KK) ? W[n*FI + k0+1] : 0.f;
      } else {
        v0 = (k0   < KK) ? W[(size_t)n*FI + k0  ] : 0.f;
        v1 = (k0+1 < KK) ? W[(size_t)n*FI + k0+1] : 0.f;
      }
      int telems = (base==WS_BP0) ? 15*50*256 : (base==WS_BPT0 ? 100*8*256 : 15*8*256);
      wsu[base + (size_t)t*telems + ii] = packbf(v0, v1);
    } else if(i < cB0 + 4*cB1 + cT0 + c6){
      int ii = i - (cB0+4*cB1+cT0); int t = ii/(H2*H1); int rem = ii - t*(H2*H1);
      int j = rem/H1; int k = rem - j*H1;
      ws[WS_FW1T + ii] = fw1[t*H1*H2 + k*H2 + j];
    } else {
      int ii = i - (cB0+4*cB1+cT0+c6); int t = ii/(HM*H2); int rem = ii - t*(HM*H2);
      int m = rem/H2; int j = rem - m*H2;
      ws[WS_FW2T + ii] = fw2[t*H2*HM + j*HM + m];
    }
  }
}

// ---- pack filter-net B-fragments for k_bwdm2 / k_fwdm ----
__global__ void __launch_bounds__(256) k_packf(const float* __restrict__ fw1,
    const float* __restrict__ fw2, float* __restrict__ ws){
  unsigned* wsu = (unsigned*)ws;
  const int c1 = NT*1024, c2 = NT*4096, c3 = NT*1024, c4 = NT*3584;
  const int total = c1 + c2 + c3 + c4;
  for(int i = blockIdx.x*blockDim.x + threadIdx.x; i < total; i += gridDim.x*blockDim.x){
    if(i < c1){                      // BF1
      int t = i/1024; int ii = i - t*1024;
      int nt = ii>>8; int lane = (ii>>2)&63; int d = ii&3;
      int n = nt*16 + (lane&15);
      int k0 = ((lane>>4)&3)*8 + 2*d;
      float v0 = (k0   < H1 && n < H2) ? fw1[t*H1*H2 + (k0  )*H2 + n] : 0.f;
      float v1 = (k0+1 < H1 && n < H2) ? fw1[t*H1*H2 + (k0+1)*H2 + n] : 0.f;
      wsu[WS_BF1B + i] = packbf(v0, v1);
    } else if(i < c1 + c2){          // BW2T
      int ii = i - c1; int t = ii/4096; ii -= t*4096;
      int nt = ii>>10; int ks = (ii>>8)&3; int lane = (ii>>2)&63; int d = ii&3;
      int n = nt*16 + (lane&15);
      int k0 = ks*32 + ((lane>>4)&3)*8 + 2*d;
      float v0 = (k0   < HM && n < H2) ? fw2[t*H2*HM + n*HM + k0  ] : 0.f;
      float v1 = (k0+1 < HM && n < H2) ? fw2[t*H2*HM + n*HM + k0+1] : 0.f;
      wsu[WS_BW2TB + ii + t*4096] = packbf(v0, v1);
    } else if(i < c1 + c2 + c3){     // BW1T
      int ii = i - c1 - c2; int t = ii/1024; ii -= t*1024;
      int nt = ii>>9; int ks = (ii>>8)&1; int lane = (ii>>2)&63; int d = ii&3;
      int n = nt*16 + (lane&15);
      int k0 = ks*32 + ((lane>>4)&3)*8 + 2*d;
      float v0 = (k0   < H2 && n < H1) ? fw1[t*H1*H2 + n*H2 + k0  ] : 0.f;
      float v1 = (k0+1 < H2 && n < H1) ? fw1[t*H1*H2 + n*H2 + k0+1] : 0.f;
      wsu[WS_BW1TB + ii + t*1024] = packbf(v0, v1);
    } else {                         // BF2
      int ii = i - c1 - c2 - c3; int t = ii/3584; ii -= t*3584;
      int nt = ii>>9; int ks = (ii>>8)&1; int lane = (ii>>2)&63; int d = ii&3;
      int n = nt*16 + (lane&15);
      int k0 = ks*32 + ((lane>>4)&3)*8 + 2*d;
      float v0 = (k0   < H2 && n < HM) ? fw2[t*H2*HM + (k0  )*HM + n] : 0.f;
      float v1 = (k0+1 < H2 && n < HM) ? fw2[t*H2*HM + (k0+1)*HM + n] : 0.f;
      wsu[WS_BF2B + ii + t*3584] = packbf(v0, v1);
    }
  }
}

__global__ void __launch_bounds__(256) k_stats(const float* __restrict__ sym,
    const int* __restrict__ types, float* __restrict__ ws){
  const int b = blockIdx.y;
  const int n0 = blockIdx.x * 64;
  const float* R = sym + ((size_t)b*NATOM + n0)*NSEL*4;
  const int* ty = types + b*NATOM;
  float ss0=0,ss20=0,xs0=0,xs20=0,ss1=0,ss21=0,xs1=0,xs21=0,c0=0,c1=0;
  for(int idx=threadIdx.x; idx<64*NSEL*4; idx+=256){
    int a = idx >> 9;
    int t = ty[n0+a];
    float v = R[idx];
    bool iss = (idx&3)==0;
    if(t==0){ if(iss){ss0+=v;ss20+=v*v;} else {xs0+=v;xs20+=v*v;} }
    else    { if(iss){ss1+=v;ss21+=v*v;} else {xs1+=v;xs21+=v*v;} }
  }
  if(threadIdx.x<64){ if(ty[n0+threadIdx.x]==0) c0=1.f; else c1=1.f; }
  ss0=wave_sum(ss0); ss20=wave_sum(ss20); xs0=wave_sum(xs0); xs20=wave_sum(xs20); c0=wave_sum(c0);
  ss1=wave_sum(ss1); ss21=wave_sum(ss21); xs1=wave_sum(xs1); xs21=wave_sum(xs21); c1=wave_sum(c1);
  if((threadIdx.x&63)==0){
    float* r0 = ws + WS_STATS_RAW + (b*2+0)*8;
    float* r1 = ws + WS_STATS_RAW + (b*2+1)*8;
    atomicAdd(r0+0,c0); atomicAdd(r0+1,ss0); atomicAdd(r0+2,ss20); atomicAdd(r0+3,xs0); atomicAdd(r0+4,xs20);
    atomicAdd(r1+0,c1); atomicAdd(r1+1,ss1); atomicAdd(r1+2,ss21); atomicAdd(r1+3,xs1); atomicAdd(r1+4,xs21);
  }
}

__global__ void k_fin_stats(float* ws){
  int i = threadIdx.x;
  if(i<8){
    float* raw = ws + WS_STATS_RAW + i*8;
    float cntf = fmaxf(raw[0], 1.f);
    float ns = cntf * (float)NSEL;
    float s_avg = raw[1]/ns, s_avg2 = raw[2]/ns;
    float x_avg = raw[3]/(ns*3.f), x_avg2 = raw[4]/(ns*3.f);
    float std_s = sqrtf(fmaxf(s_avg2 - s_avg*s_avg, 0.f)) + 1e-8f;
    float std_x = sqrtf(fmaxf(x_avg2 - x_avg*x_avg, 0.f)) + 1e-8f;
    float* fin = ws + WS_STATS_FIN + i*8;
    fin[0]=s_avg; fin[1]=1.f/std_s; fin[2]=1.f/std_x; fin[3]=cntf; fin[4]=raw[0];
  }
}

__global__ void k_index(const int* __restrict__ types, float* __restrict__ ws){
  int b = blockIdx.x;
  int rc0 = (int)ws[WS_STATS_FIN + (b*2)*8 + 4];
  int pad0 = (rc0+63)&~63;
  int* ctr = (int*)ws + WS_CTR;
  int* idx = (int*)ws + WS_IDX;
  for(int n=threadIdx.x;n<NATOM;n+=256){
    int t = types[b*NATOM+n];
    int pos = atomicAdd(&ctr[b*2+t],1);
    idx[b*1152 + (t ? pad0+pos : pos)] = n;
  }
}

// ---- descriptor forward via MFMA filter layers (storeGT path) ----
__global__ void __launch_bounds__(128) k_fwdm(const float* __restrict__ sym, const int* __restrict__ types,
    const float* __restrict__ fw0,const float* __restrict__ fb0,
    const float* __restrict__ fb1,const float* __restrict__ fb2,
    float* __restrict__ ws){
  extern __shared__ char fraw[];
  float* Rn4 = (float*)fraw;                              // 512 f -> 2048
  float* RG4 = (float*)(fraw + 2048);                     // 400 f -> 3648
  float* red = (float*)(fraw + 3648);                     // 8 f  -> 3680
  unsigned short* a2F = (unsigned short*)(fraw + 3680);   // [128][66] -> 20576
  unsigned* a2Fu = (unsigned*)(fraw + 3680);              // stride 33 uints
  unsigned* a1L = (unsigned*)(fraw + 20576);              // [128][17] uints (aliases Gl)
  unsigned short* Gl = (unsigned short*)(fraw + 20576);   // [128][GSTR] ushort -> 48224

  const int bid = blockIdx.x;
  const int b = bid >> 10;
  int t = types[bid];
  t = __builtin_amdgcn_readfirstlane(t);
  const float* fin = ws + WS_STATS_FIN + (b*2+t)*8;
  const float avg_s = fin[0], inv_ss = fin[1], inv_sx = fin[2];
  const int s = threadIdx.x;
  const int wave = s>>6, lane = s&63, lw = lane&15, lg = lane>>4;

  const float* W0 = fw0 + t*H1; const float* B0 = fb0 + t*H1;
  const float* B1 = fb1 + t*H2; const float* B2 = fb2 + t*HM;
  const unsigned* wsu = (const unsigned*)ws;
  const bf16x8* BF1 = (const bf16x8*)(wsu + WS_BF1B) + t*4*64;
  const bf16x8* BF2 = (const bf16x8*)(wsu + WS_BF2B) + t*14*64;

  float4 R4 = *(const float4*)&sym[(size_t)bid*NSEL*4 + s*4];
  float rn0 = (R4.x-avg_s)*inv_ss, rn1 = R4.y*inv_sx, rn2 = R4.z*inv_sx, rn3 = R4.w*inv_sx;
  *(float4*)&Rn4[s*4] = make_float4(rn0,rn1,rn2,rn3);

  {
    float a1r[H1];
#pragma unroll
    for(int kk=0;kk<H1;kk++) a1r[kk] = ftanh(rn0*W0[kk] + B0[kk]);
    unsigned* rw = a1L + s*17;
#pragma unroll
    for(int q=0;q<12;q++) rw[q] = packbf(a1r[2*q], a1r[2*q+1]);
    rw[12] = packbf(a1r[24], 0.f);
    rw[13]=0; rw[14]=0; rw[15]=0; rw[16]=0;
  }
  __syncthreads();

  const f32x4 fz = {0.f,0.f,0.f,0.f};
  for(int nt=0;nt<4;nt++){
    f32x4 acc[4];
#pragma unroll
    for(int mt=0;mt<4;mt++){
      int MT = wave*4 + mt;
      bf16x8 af = *(const bf16x8*)&a1L[(MT*16+lw)*17 + lg*4];
      acc[mt] = __builtin_amdgcn_mfma_f32_16x16x32_bf16(af, BF1[nt*64+lane], fz, 0,0,0);
    }
    int col = nt*16 + lw;
    float bias = (col<H2) ? B1[col] : 0.f;
#pragma unroll
    for(int mt=0;mt<4;mt++)
#pragma unroll
      for(int r=0;r<4;r++){
        int rw = (wave*4+mt)*16 + lg*4 + r;
        float v = (col<H2) ? ftanh(acc[mt][r] + bias) : 0.f;
        a2F[rw*66 + col] = f2bf(v);
      }
  }
  __syncthreads();
  for(int nt=0;nt<7;nt++){
    f32x4 acc[4];
#pragma unroll
    for(int mt=0;mt<4;mt++) acc[mt] = fz;
    for(int ks=0;ks<2;ks++){
#pragma unroll
      for(int mt=0;mt<4;mt++){
        int MT = wave*4 + mt;
        bf16x8 af = *(const bf16x8*)&a2Fu[(MT*16+lw)*33 + ks*16 + lg*4];
        acc[mt] = __builtin_amdgcn_mfma_f32_16x16x32_bf16(af, BF2[(nt*2+ks)*64+lane], acc[mt], 0,0,0);
      }
    }
    int col = nt*16 + lw;
    if(col < HM){
      float bias = B2[col];
#pragma unroll
      for(int mt=0;mt<4;mt++)
#pragma unroll
        for(int r=0;r<4;r++){
          int rw = (wave*4+mt)*16 + lg*4 + r;
          Gl[rw*GSTR + col] = f2bf(ftanh(acc[mt][r] + bias));
        }
    }
  }
  __syncthreads();
  if(s < HM){
    const int m = s;
    float a0=0,b0=0,c0=0,d0=0;
    for(int sn=0;sn<NSEL;sn++){
      float4 rn = *(const float4*)&Rn4[sn*4];
      float g = bf2f(Gl[sn*GSTR+m]);
      a0 += rn.x*g; b0 += rn.y*g; c0 += rn.z*g; d0 += rn.w*g;
    }
    *(float4*)&RG4[m*4] = make_float4(a0,b0,c0,d0);
  }
  __syncthreads();
  for(int i=s;i<HM*4;i+=128) ws[WS_RGB + (size_t)bid*(HM*4) + i] = RG4[i];
  {
    unsigned* GT = (unsigned*)ws + WS_GTB + (size_t)bid*((HM/2)*NSEL);
    for(int i=s;i<(HM/2)*NSEL;i+=128){
      int mp = i >> 7, ss = i & 127;
      GT[i] = *(const unsigned*)&Gl[ss*GSTR + 2*mp];
    }
  }
  float lsum=0,lsum2=0;
  float* gout = ws + WS_G + (size_t)bid*GF;
  for(int i=s;i<GF;i+=128){
    int m=i>>4, a=i&15;
    float4 rm = *(const float4*)&RG4[m*4];
    float4 ra = *(const float4*)&RG4[a*4];
    float gv = rm.x*ra.x + rm.y*ra.y + rm.z*ra.z + rm.w*ra.w;
    gout[i]=gv; lsum+=gv; lsum2+=gv*gv;
  }
  lsum = block_sum2(lsum, red);
  lsum2 = block_sum2(lsum2, red);
  if(s==0){
    atomicAdd(&ws[WS_MUSD_RAW + (b*2+t)*2 + 0], lsum);
    atomicAdd(&ws[WS_MUSD_RAW + (b*2+t)*2 + 1], lsum2);
  }
}

// ---- scalar descriptor forward (fallback) ----
__global__ void __launch_bounds__(128) k_fwd(const float* __restrict__ sym, const int* __restrict__ types,
    const float* __restrict__ fw0,const float* __restrict__ fb0,
    const float* __restrict__ fb1,const float* __restrict__ fb2,
    float* __restrict__ ws){
  __shared__ float Rn4[NSEL*4];
  __shared__ unsigned short Gl[NSEL*GSTR];
  __shared__ float RG4[HM*4];
  __shared__ float red[8];

  const int bid = blockIdx.x;
  const int b = bid >> 10;
  int t = types[bid];
  t = __builtin_amdgcn_readfirstlane(t);
  const float* fin = ws + WS_STATS_FIN + (b*2+t)*8;
  const float avg_s = fin[0], inv_ss = fin[1], inv_sx = fin[2];
  const int s = threadIdx.x;

  const float* W0 = fw0 + t*H1; const float* B0 = fb0 + t*H1;
  const float* B1 = fb1 + t*H2; const float* B2 = fb2 + t*HM;
  const float* W1T = ws + WS_FW1T + t*H2*H1;
  const float* W2T = ws + WS_FW2T + t*HM*H2;

  float4 R4 = *(const float4*)&sym[(size_t)bid*NSEL*4 + s*4];
  float rn0 = (R4.x-avg_s)*inv_ss, rn1 = R4.y*inv_sx, rn2 = R4.z*inv_sx, rn3 = R4.w*inv_sx;
  *(float4*)&Rn4[s*4] = make_float4(rn0,rn1,rn2,rn3);

  float a1[H1];
#pragma unroll
  for(int k=0;k<H1;k++) a1[k] = ftanh(rn0*W0[k] + B0[k]);
  float a2[H2];
#pragma unroll
  for(int j=0;j<H2;j++){
    float acc = B1[j];
    const float* wr = W1T + j*H1;
#pragma unroll
    for(int k=0;k<H1;k++) acc += a1[k]*wr[k];
    a2[j] = ftanh(acc);
  }
  for(int m=0;m<HM;m+=4){
    const float* wr0 = W2T + m*H2; const float* wr1 = wr0 + H2;
    const float* wr2 = wr1 + H2;  const float* wr3 = wr2 + H2;
    float acc0 = B2[m], acc1 = B2[m+1], acc2 = B2[m+2], acc3 = B2[m+3];
#pragma unroll
    for(int j=0;j<H2;j++){
      float aj = a2[j];
      acc0 += aj*wr0[j]; acc1 += aj*wr1[j]; acc2 += aj*wr2[j]; acc3 += aj*wr3[j];
    }
    unsigned u0 = (unsigned)f2bf(ftanh(acc0)) | ((unsigned)f2bf(ftanh(acc1))<<16);
    unsigned u1 = (unsigned)f2bf(ftanh(acc2)) | ((unsigned)f2bf(ftanh(acc3))<<16);
    *(unsigned*)&Gl[s*GSTR + m] = u0;
    *(unsigned*)&Gl[s*GSTR + m + 2] = u1;
  }
  __syncthreads();
  if(s < HM){
    const int m = s;
    float a0=0,b0=0,c0=0,d0=0;
    for(int sn=0;sn<NSEL;sn++){
      float4 rn = *(const float4*)&Rn4[sn*4];
      float g = bf2f(Gl[sn*GSTR+m]);
      a0 += rn.x*g; b0 += rn.y*g; c0 += rn.z*g; d0 += rn.w*g;
    }
    *(float4*)&RG4[m*4] = make_float4(a0,b0,c0,d0);
  }
  __syncthreads();
  for(int i=s;i<HM*4;i+=128) ws[WS_RGB + (size_t)bid*(HM*4) + i] = RG4[i];
  float lsum=0,lsum2=0;
  float* gout = ws + WS_G + (size_t)bid*GF;
  for(int i=s;i<GF;i+=128){
    int m=i>>4, a=i&15;
    float4 rm = *(const float4*)&RG4[m*4];
    float4 ra = *(const float4*)&RG4[a*4];
    float gv = rm.x*ra.x + rm.y*ra.y + rm.z*ra.z + rm.w*ra.w;
    gout[i]=gv; lsum+=gv; lsum2+=gv*gv;
  }
  lsum = block_sum2(lsum, red);
  lsum2 = block_sum2(lsum2, red);
  if(s==0){
    atomicAdd(&ws[WS_MUSD_RAW + (b*2+t)*2 + 0], lsum);
    atomicAdd(&ws[WS_MUSD_RAW + (b*2+t)*2 + 1], lsum2);
  }
}

__global__ void k_fin_musd(float* ws){
  int i=threadIdx.x;
  if(i<8){
    float cntf = ws[WS_STATS_FIN + i*8 + 3];
    float denom = cntf * (float)GF;
    float Sg = ws[WS_MUSD_RAW + i*2], Sg2 = ws[WS_MUSD_RAW + i*2+1];
    float mu = Sg/denom, mu2 = Sg2/denom;
    float var = fmaxf(mu2 - mu*mu, 0.f);
    float r = sqrtf(var); float sd = r + 1e-8f;
    float* mf = ws + WS_MUSD_FIN + i*4;
    mf[0]=mu; mf[1]=1.f/sd; mf[2]=r; mf[3]=sd;
  }
}

// ---- fitting net via MFMA: fwd+bwd through dz1; dz1 image stored for k_pm ----
__global__ void __launch_bounds__(256) k_fitm(
    const float* __restrict__ gb0,const float* __restrict__ gb1,
    const float* __restrict__ gb2,
    const float* __restrict__ gwo,const float* __restrict__ gbo,
    float* __restrict__ ws){
  extern __shared__ unsigned short lb[];
  unsigned short* h1S = lb;              // [64][264]
  unsigned short* h2S = lb + 16896;
  unsigned short* dzA = lb + 33792;

  const int b = blockIdx.x / NGRP64;
  const int grp = blockIdx.x - b*NGRP64;
  int rc0 = (int)ws[WS_STATS_FIN + (b*2)*8 + 4];
  int rc1 = (int)ws[WS_STATS_FIN + (b*2+1)*8 + 4];
  rc0 = __builtin_amdgcn_readfirstlane(rc0);
  rc1 = __builtin_amdgcn_readfirstlane(rc1);
  const int pad0 = (rc0+63)&~63;
  const int tend = pad0 + ((rc1+63)&~63);
  const int slot0 = grp*64;
  if(slot0 >= tend) return;
  const int t = (slot0 >= pad0) ? 1 : 0;

  const float* mf = ws + WS_MUSD_FIN + (b*2+t)*4;
  const float mu = mf[0], isd = mf[1];

  const int tid = threadIdx.x;
  const int wave = tid>>6, lane = tid&63;
  const int lw = lane&15, lg = lane>>4;
  const int mRowBase = wave*16 + lg*4;

  const int* idx = (const int*)ws + WS_IDX + b*1152;
  int arow = idx[slot0 + wave*16 + lw];
  int rowSafe = arow<0?0:arow;
  const float* yrowA = ws + WS_G + (size_t)(b*NATOM + rowSafe)*GF;
  int idC[4];
#pragma unroll
  for(int r=0;r<4;r++) idC[r] = idx[slot0 + wave*16 + lg*4 + r];

  const unsigned* wsu = (const unsigned*)ws;
  const bf16x8* BP0  = (const bf16x8*)(wsu + WS_BP0)  + (size_t)t*15*50*64;
  const bf16x8* BP1  = (const bf16x8*)(wsu + WS_BP1)  + t*15*8*64;
  const bf16x8* BP2  = (const bf16x8*)(wsu + WS_BP2)  + t*15*8*64;
  const bf16x8* BPT2 = (const bf16x8*)(wsu + WS_BPT2) + t*15*8*64;
  const bf16x8* BPT1 = (const bf16x8*)(wsu + WS_BPT1) + t*15*8*64;

  for(int i=tid;i<64*24;i+=256){
    int r = i/24, c = 240 + (i - (i/24)*24);
    h1S[r*264+c]=0; h2S[r*264+c]=0; dzA[r*264+c]=0;
  }

  f32x4 acc[15];
  const f32x4 fz = {0.f,0.f,0.f,0.f};
#pragma unroll
  for(int nt=0;nt<15;nt++) acc[nt] = fz;
  for(int ks=0;ks<50;ks++){
    float4 y0 = *(const float4*)(yrowA + ks*32 + lg*8);
    float4 y1 = *(const float4*)(yrowA + ks*32 + lg*8 + 4);
    union{ unsigned u[4]; bf16x8 v; } A;
    A.u[0]=packbf((y0.x-mu)*isd,(y0.y-mu)*isd); A.u[1]=packbf((y0.z-mu)*isd,(y0.w-mu)*isd);
    A.u[2]=packbf((y1.x-mu)*isd,(y1.y-mu)*isd); A.u[3]=packbf((y1.z-mu)*isd,(y1.w-mu)*isd);
#pragma unroll
    for(int nt=0;nt<15;nt++)
      acc[nt] = __builtin_amdgcn_mfma_f32_16x16x32_bf16(A.v, BP0[(nt*50+ks)*64+lane], acc[nt], 0,0,0);
  }
#pragma unroll
  for(int nt=0;nt<15;nt++){
    float bias = gb0[t*FI + nt*16 + lw];
#pragma unroll
    for(int r=0;r<4;r++){
      float h = ftanh(acc[nt][r] + bias);
      h1S[(mRowBase+r)*264 + nt*16 + lw] = f2bf(h);
    }
  }
  __syncthreads();
#pragma unroll
  for(int nt=0;nt<15;nt++) acc[nt] = fz;
  for(int ks=0;ks<8;ks++){
    bf16x8 a = *(const bf16x8*)&h1S[(wave*16+lw)*264 + ks*32 + lg*8];
#pragma unroll
    for(int nt=0;nt<15;nt++)
      acc[nt] = __builtin_amdgcn_mfma_f32_16x16x32_bf16(a, BP1[(nt*8+ks)*64+lane], acc[nt], 0,0,0);
  }
#pragma unroll
  for(int nt=0;nt<15;nt++){
    float bias = gb1[t*FI + nt*16 + lw];
#pragma unroll
    for(int r=0;r<4;r++){
      float h = ftanh(acc[nt][r] + bias);
      h2S[(mRowBase+r)*264 + nt*16 + lw] = f2bf(h);
    }
  }
  __syncthreads();
#pragma unroll
  for(int nt=0;nt<15;nt++) acc[nt] = fz;
  for(int ks=0;ks<8;ks++){
    bf16x8 a = *(const bf16x8*)&h2S[(wave*16+lw)*264 + ks*32 + lg*8];
#pragma unroll
    for(int nt=0;nt<15;nt++)
      acc[nt] = __builtin_amdgcn_mfma_f32_16x16x32_bf16(a, BP2[(nt*8+ks)*64+lane], acc[nt], 0,0,0);
  }
  float pe[4] = {0.f,0.f,0.f,0.f};
#pragma unroll
  for(int nt=0;nt<15;nt++){
    float bias = gb2[t*FI + nt*16 + lw];
    float wo = gwo[t*FI + nt*16 + lw];
#pragma unroll
    for(int r=0;r<4;r++){
      float h = ftanh(acc[nt][r] + bias);
      pe[r] += h*wo;
      float d3 = wo*(1.f - h*h);
      dzA[(mRowBase+r)*264 + nt*16 + lw] = f2bf(d3);
    }
  }
#pragma unroll
  for(int o=1;o<16;o<<=1){
#pragma unroll
    for(int r=0;r<4;r++) pe[r] += __shfl_xor(pe[r], o, 64);
  }
  if(lw==0){
#pragma unroll
    for(int r=0;r<4;r++) if(idC[r]>=0) ws[WS_EBUF + b*NATOM + idC[r]] = pe[r] + gbo[t];
  }
  __syncthreads();
#pragma unroll
  for(int nt=0;nt<15;nt++) acc[nt] = fz;
  for(int ks=0;ks<8;ks++){
    bf16x8 a = *(const bf16x8*)&dzA[(wave*16+lw)*264 + ks*32 + lg*8];
#pragma unroll
    for(int nt=0;nt<15;nt++)
      acc[nt] = __builtin_amdgcn_mfma_f32_16x16x32_bf16(a, BPT2[(nt*8+ks)*64+lane], acc[nt], 0,0,0);
  }
#pragma unroll
  for(int nt=0;nt<15;nt++){
#pragma unroll
    for(int r=0;r<4;r++){
      float h2 = bf2f(h2S[(mRowBase+r)*264 + nt*16 + lw]);
      acc[nt][r] *= (1.f - h2*h2);
    }
  }
  __syncthreads();
#pragma unroll
  for(int nt=0;nt<15;nt++){
#pragma unroll
    for(int r=0;r<4;r++) dzA[(mRowBase+r)*264 + nt*16 + lw] = f2bf(acc[nt][r]);
  }
  __syncthreads();
#pragma unroll
  for(int nt=0;nt<15;nt++) acc[nt] = fz;
  for(int ks=0;ks<8;ks++){
    bf16x8 a = *(const bf16x8*)&dzA[(wave*16+lw)*264 + ks*32 + lg*8];
#pragma unroll
    for(int nt=0;nt<15;nt++)
      acc[nt] = __builtin_amdgcn_mfma_f32_16x16x32_bf16(a, BPT1[(nt*8+ks)*64+lane], acc[nt], 0,0,0);
  }
#pragma unroll
  for(int nt=0;nt<15;nt++){
#pragma unroll
    for(int r=0;r<4;r++){
      float h1 = bf2f(h1S[(mRowBase+r)*264 + nt*16 + lw]);
      acc[nt][r] *= (1.f - h1*h1);
    }
  }
  __syncthreads();
#pragma unroll
  for(int nt=0;nt<15;nt++){
#pragma unroll
    for(int r=0;r<4;r++) dzA[(mRowBase+r)*264 + nt*16 + lw] = f2bf(acc[nt][r]);
  }
  __syncthreads();
  // store dz1 frag image for k_pm
  {
    unsigned* dzOut = (unsigned*)ws + WS_DZ1 + (size_t)blockIdx.x*8448;
    const unsigned* dzAu = (const unsigned*)dzA;
    for(int i=tid;i<8448;i+=256) dzOut[i] = dzAu[i];
  }
}

// ---- p = dz1 @ gw0^T, N-chunked across blocks (all-CU coverage) + S1/Sy ----
__global__ void __launch_bounds__(256) k_pm(float* __restrict__ ws){
  extern __shared__ unsigned short lb[];   // dzA image [64][264]
  unsigned short* dzA = lb;
  __shared__ float red[4];

  const int gid = blockIdx.x / PCH;
  const int chunk = blockIdx.x - gid*PCH;
  const int b = gid / NGRP64;
  const int grp = gid - b*NGRP64;
  int rc0 = (int)ws[WS_STATS_FIN + (b*2)*8 + 4];
  int rc1 = (int)ws[WS_STATS_FIN + (b*2+1)*8 + 4];
  rc0 = __builtin_amdgcn_readfirstlane(rc0);
  rc1 = __builtin_amdgcn_readfirstlane(rc1);
  const int pad0 = (rc0+63)&~63;
  const int tend = pad0 + ((rc1+63)&~63);
  const int slot0 = grp*64;
  if(slot0 >= tend) return;
  const int t = (slot0 >= pad0) ? 1 : 0;

  const float* mf = ws + WS_MUSD_FIN + (b*2+t)*4;
  const float mu = mf[0], isd = mf[1];
  const int tid = threadIdx.x;
  const int wave = tid>>6, lane = tid&63, lw = lane&15, lg = lane>>4;

  const int* idx = (const int*)ws + WS_IDX + b*1152;
  int idC[4];
#pragma unroll
  for(int r=0;r<4;r++) idC[r] = idx[slot0 + wave*16 + lg*4 + r];

  const unsigned* wsu = (const unsigned*)ws;
  const bf16x8* BPT0 = (const bf16x8*)(wsu + WS_BPT0) + (size_t)t*100*8*64;

  // load dz1 image
  {
    const unsigned* src = (const unsigned*)ws + WS_DZ1 + (size_t)gid*8448;
    unsigned* dst = (unsigned*)lb;
    for(int i=tid;i<8448;i+=256) dst[i] = src[i];
  }
  __syncthreads();

  const f32x4 fz = {0.f,0.f,0.f,0.f};
  const float* yG = ws + WS_G + (size_t)b*NATOM*GF;
  float* pP = ws + WS_P + (size_t)b*NATOM*GF;
  float s1t=0.f, syt=0.f;
  for(int sc=0;sc<2;sc++){
    int c0 = chunk*20 + sc*10;
    f32x4 pc[10];
#pragma unroll
    for(int j=0;j<10;j++) pc[j] = fz;
    for(int ks=0;ks<8;ks++){
      bf16x8 a = *(const bf16x8*)&dzA[(wave*16+lw)*264 + ks*32 + lg*8];
#pragma unroll
      for(int j=0;j<10;j++)
        pc[j] = __builtin_amdgcn_mfma_f32_16x16x32_bf16(a, BPT0[((c0+j)*8+ks)*64+lane], pc[j], 0,0,0);
    }
#pragma unroll
    for(int j=0;j<10;j++){
      int n = (c0+j)*16 + lw;
#pragma unroll
      for(int r=0;r<4;r++){
        if(idC[r]>=0){
          float pv = pc[j][r];
          size_t off = (size_t)idC[r]*GF + n;
          pP[off] = pv;
          s1t += pv;
          syt += pv * (yG[off]-mu)*isd;
        }
      }
    }
  }
  s1t = block_sum4(s1t, red);
  syt = block_sum4(syt, red);
  if(tid==0){
    atomicAdd(&ws[WS_S_RAW+(b*2+t)*2+0], s1t);
    atomicAdd(&ws[WS_S_RAW+(b*2+t)*2+1], syt);
  }
}

// ---- descriptor backward via MFMA, compact LDS (r19 proven) + async GT->LDS staging (r22):
//      1 atom/block, 128 thr. GT rows prefetched via global_load_lds at kernel entry;
//      all 26 loads/wave in flight -> one latency, drained at first barrier. ----
__global__ void __launch_bounds__(128) k_bwdm2(const float* __restrict__ sym,
    const float* __restrict__ dxp,const float* __restrict__ dyp,const float* __restrict__ dzp,
    const int* __restrict__ types,
    const float* __restrict__ fw0,const float* __restrict__ fb0,
    const float* __restrict__ fb1,
    float* __restrict__ ws, float* __restrict__ out){
  extern __shared__ char lraw[];
  float* dRG4 = (float*)lraw;
  float* red  = (float*)(lraw + 1600);
  float* dgb  = (float*)(lraw + 1664);
  float* RG4  = (float*)(lraw + 8464);
  unsigned short* a2L = (unsigned short*)(lraw + 1664);    // stride 51
  unsigned* dz2u = (unsigned*)(lraw + 14720);              // stride 25
  unsigned short* dz2s = (unsigned short*)(lraw + 14720);  // stride 50
  unsigned* ML = (unsigned*)(lraw + 27648);                // stride 51
  unsigned short* dz1L = (unsigned short*)(lraw + 27648);  // stride 28
  unsigned* GTL = (unsigned*)(lraw + 54016);               // [50][128] staged GT -> 79616

  const int bid = blockIdx.x;
  const int b = bid >> 10;
  const int s = threadIdx.x;
  const int wave = s>>6, lane = s&63, lw = lane&15, lg = lane>>4;

  // ---- async-stage GT rows (depends only on bid): 13 wide loads per wave,
  //      16B/lane, fire-and-forget into LDS; drained by first __syncthreads().
  {
    const unsigned* GTg = (const unsigned*)ws + WS_GTB + (size_t)bid*((HM/2)*NSEL);
    for(int qp = wave; qp < 25; qp += 2){
      const unsigned* gsrc = GTg + qp*256 + lane*4;
      unsigned* ldst = GTL + qp*256;
      __builtin_amdgcn_global_load_lds((GU*)gsrc, (LU*)ldst, 16, 0, 0);
    }
  }

  int t = types[bid];
  t = __builtin_amdgcn_readfirstlane(t);
  const float* fin = ws + WS_STATS_FIN + (b*2+t)*8;
  const float avg_s=fin[0], inv_ss=fin[1], inv_sx=fin[2], cntf=fin[3];
  const float* mf = ws + WS_MUSD_FIN + (b*2+t)*4;
  const float mu=mf[0], inv_sd=mf[1], rr=mf[2];
  const float S1 = ws[WS_S_RAW + (b*2+t)*2 + 0];
  const float Sy = ws[WS_S_RAW + (b*2+t)*2 + 1];
  const float denom = cntf * (float)GF;
  const float c1 = S1/denom;
  const float c2 = (rr>0.f) ? (Sy/denom)/rr : 0.f;

  const float* W0 = fw0 + t*H1; const float* B0 = fb0 + t*H1;
  const float* B1f = fb1 + t*H2;
  const unsigned* wsu = (const unsigned*)ws;
  const bf16x8* BF1  = (const bf16x8*)(wsu + WS_BF1B)  + t*4*64;
  const bf16x8* BW2T = (const bf16x8*)(wsu + WS_BW2TB) + t*16*64;
  const bf16x8* BW1T = (const bf16x8*)(wsu + WS_BW1TB) + t*4*64;

  if(s < 32) ((unsigned*)(lraw + 14720))[128*25 + s] = 0;
  if(s < 64) ML[128*51 + s] = 0;

  for(int i=s;i<HM*4;i+=128) RG4[i] = ws[WS_RGB + (size_t)bid*(HM*4) + i];
  __syncthreads();
  const float* p = ws + WS_P + (size_t)bid*GF;
  for(int i=s;i<GF;i+=128){
    int m=i>>4, a=i&15;
    float4 rm = *(const float4*)&RG4[m*4];
    float4 ra = *(const float4*)&RG4[a*4];
    float gv = rm.x*ra.x + rm.y*ra.y + rm.z*ra.z + rm.w*ra.w;
    float yv = (gv-mu)*inv_sd;
    dgb[m*17+a] = (p[i]-c1)*inv_sd - yv*c2;
  }
  __syncthreads();
  if(s < HM){
    const int m = s;
    float a0=0,b0=0,c0=0,d0=0;
#pragma unroll
    for(int a=0;a<AX;a++){
      float d = dgb[m*17+a];
      float4 r = *(const float4*)&RG4[a*4];
      a0 += d*r.x; b0 += d*r.y; c0 += d*r.z; d0 += d*r.w;
    }
    if(m<AX){
      for(int mp=0;mp<HM;mp++){
        float d = dgb[mp*17+m];
        float4 r = *(const float4*)&RG4[mp*4];
        a0 += d*r.x; b0 += d*r.y; c0 += d*r.z; d0 += d*r.w;
      }
    }
    *(float4*)&dRG4[m*4] = make_float4(a0,b0,c0,d0);
  }
  float4 R4 = *(const float4*)&sym[(size_t)bid*NSEL*4 + s*4];
  float rn0 = (R4.x-avg_s)*inv_ss, rn1 = R4.y*inv_sx, rn2 = R4.z*inv_sx, rn3 = R4.w*inv_sx;
  {
    float a1r[H1];
#pragma unroll
    for(int kk=0;kk<H1;kk++) a1r[kk] = ftanh(rn0*W0[kk] + B0[kk]);
    unsigned* row = ML + s*51;
#pragma unroll
    for(int q=0;q<12;q++) row[q] = packbf(a1r[2*q], a1r[2*q+1]);
    row[12] = packbf(a1r[24], 0.f);
    row[13]=0; row[14]=0; row[15]=0; row[16]=0;
  }
  __syncthreads();

  const f32x4 fz = {0.f,0.f,0.f,0.f};
  // ---- C: a2 = tanh(a1 @ fw1 + b1) -> a2L (cols < 50 only)
  for(int nt=0;nt<4;nt++){
    f32x4 acc[4];
#pragma unroll
    for(int mt=0;mt<4;mt++){
      bf16x8 af = *(const bf16x8*)&ML[((wave*4+mt)*16+lw)*51 + lg*4];
      acc[mt] = __builtin_amdgcn_mfma_f32_16x16x32_bf16(af, BF1[nt*64+lane], fz, 0,0,0);
    }
    int col = nt*16 + lw;
    if(col < H2){
      float bias = B1f[col];
#pragma unroll
      for(int mt=0;mt<4;mt++)
#pragma unroll
        for(int r=0;r<4;r++){
          int rw = (wave*4+mt)*16 + lg*4 + r;
          a2L[rw*51 + col] = f2bf(ftanh(acc[mt][r] + bias));
        }
    }
  }
  __syncthreads();
  // ---- D: dz3 -> ML rows; fused drn. GT read from LDS (GTL), conflict-free.
  float drn0=0,drn1=0,drn2=0,drn3=0;
  {
    unsigned* row = ML + s*51;
    for(int q=0;q<50;q++){
      int m0 = 2*q;
      unsigned u = GTL[q*128 + s];
      float g0 = bflo(u), g1 = bfhi(u);
      float4 dm0 = *(const float4*)&dRG4[m0*4];
      float4 dm1 = *(const float4*)&dRG4[(m0+1)*4];
      drn0 += dm0.x*g0 + dm1.x*g1;
      drn1 += dm0.y*g0 + dm1.y*g1;
      drn2 += dm0.z*g0 + dm1.z*g1;
      drn3 += dm0.w*g0 + dm1.w*g1;
      float d30 = (dm0.x*rn0 + dm0.y*rn1 + dm0.z*rn2 + dm0.w*rn3)*(1.f-g0*g0);
      float d31 = (dm1.x*rn0 + dm1.y*rn1 + dm1.z*rn2 + dm1.w*rn3)*(1.f-g1*g1);
      row[q] = packbf(d30, d31);
    }
    row[50] = 0;
  }
  __syncthreads();
  // ---- E: dz2 = dz3 @ fw2^T, deriv vs a2L -> dz2s (cols < 50)
  for(int nt=0;nt<4;nt++){
    f32x4 acc[4];
#pragma unroll
    for(int mt=0;mt<4;mt++) acc[mt] = fz;
    for(int ks=0;ks<4;ks++){
#pragma unroll
      for(int mt=0;mt<4;mt++){
        bf16x8 af = *(const bf16x8*)&ML[((wave*4+mt)*16+lw)*51 + ks*16 + lg*4];
        acc[mt] = __builtin_amdgcn_mfma_f32_16x16x32_bf16(af, BW2T[(nt*4+ks)*64+lane], acc[mt], 0,0,0);
      }
    }
    int col = nt*16 + lw;
    if(col < H2){
#pragma unroll
      for(int mt=0;mt<4;mt++)
#pragma unroll
        for(int r=0;r<4;r++){
          int rw = (wave*4+mt)*16 + lg*4 + r;
          float a2v = bf2f(a2L[rw*51 + col]);
          dz2s[rw*50 + col] = f2bf(acc[mt][r]*(1.f - a2v*a2v));
        }
    }
  }
  __syncthreads();
  // ---- F: dz1 = dz2 @ fw1^T -> dz1L (aliases ML)
  for(int nt2=0;nt2<2;nt2++){
    f32x4 acc[4];
#pragma unroll
    for(int mt=0;mt<4;mt++) acc[mt] = fz;
    for(int ks2=0;ks2<2;ks2++){
#pragma unroll
      for(int mt=0;mt<4;mt++){
        bf16x8 af = *(const bf16x8*)&dz2u[((wave*4+mt)*16+lw)*25 + ks2*16 + lg*4];
        acc[mt] = __builtin_amdgcn_mfma_f32_16x16x32_bf16(af, BW1T[(nt2*2+ks2)*64+lane], acc[mt], 0,0,0);
      }
    }
    int col = nt2*16 + lw;
    if(col < 28){
#pragma unroll
      for(int mt=0;mt<4;mt++)
#pragma unroll
        for(int r=0;r<4;r++){
          int rw = (wave*4+mt)*16 + lg*4 + r;
          dz1L[rw*28 + col] = f2bf((col<H1) ? acc[mt][r] : 0.f);
        }
    }
  }
  __syncthreads();
  // ---- G: ds per row (a1 recomputed from rn0)
  {
    float ds = 0.f;
#pragma unroll
    for(int kk=0;kk<H1;kk++){
      float w0v = W0[kk];
      float a1v = ftanh(rn0*w0v + B0[kk]);
      float d1 = bf2f(dz1L[s*28 + kk]);
      ds += d1*(1.f - a1v*a1v)*w0v;
    }
    drn0 += ds;
  }
  // ---- H: forces
  float w0 = drn0*inv_ss, w1 = drn1*inv_sx, w2 = drn2*inv_sx, w3 = drn3*inv_sx;
  float4 X = *(const float4*)&dxp[(size_t)bid*NSEL*4 + s*4];
  float4 Y = *(const float4*)&dyp[(size_t)bid*NSEL*4 + s*4];
  float4 Z = *(const float4*)&dzp[(size_t)bid*NSEL*4 + s*4];
  float fx = w0*X.x + w1*X.y + w2*X.z + w3*X.w;
  float fy = w0*Y.x + w1*Y.y + w2*Y.z + w3*Y.w;
  float fz2 = w0*Z.x + w1*Z.y + w2*Z.z + w3*Z.w;
  fx = wave_sum(fx); fy = wave_sum(fy); fz2 = wave_sum(fz2);
  __syncthreads();
  if((s&63)==0){ int w=s>>6; red[w*3+0]=fx; red[w*3+1]=fy; red[w*3+2]=fz2; }
  __syncthreads();
  if(s==0){
    float* F = out + 4 + (size_t)bid*3;
    F[0] = -(red[0]+red[3]);
    F[1] = -(red[1]+red[4]);
    F[2] = -(red[2]+red[5]);
  }
}

// ---- scalar fallback backward (recompute G) ----
__global__ void __launch_bounds__(128) k_bwd0(const float* __restrict__ sym,
    const float* __restrict__ dxp,const float* __restrict__ dyp,const float* __restrict__ dzp,
    const int* __restrict__ types,
    const float* __restrict__ fw0,const float* __restrict__ fb0,
    const float* __restrict__ fw1,const float* __restrict__ fb1,
    const float* __restrict__ fb2,
    float* __restrict__ ws, float* __restrict__ out){
  __shared__ float RG4[HM*4];
  __shared__ float dgb[HM*17];
  __shared__ float dRG4[HM*4];
  __shared__ float red[8];

  const int bid = blockIdx.x;
  const int b = bid >> 10;
  int t = types[bid];
  t = __builtin_amdgcn_readfirstlane(t);
  const float* fin = ws + WS_STATS_FIN + (b*2+t)*8;
  const float avg_s=fin[0], inv_ss=fin[1], inv_sx=fin[2], cntf=fin[3];
  const float* mf = ws + WS_MUSD_FIN + (b*2+t)*4;
  const float mu=mf[0], inv_sd=mf[1], rr=mf[2];
  const float S1 = ws[WS_S_RAW + (b*2+t)*2 + 0];
  const float Sy = ws[WS_S_RAW + (b*2+t)*2 + 1];
  const float denom = cntf * (float)GF;
  const float c1 = S1/denom;
  const float c2 = (rr>0.f) ? (Sy/denom)/rr : 0.f;
  const int s = threadIdx.x;

  const float* W0 = fw0 + t*H1; const float* B0 = fb0 + t*H1;
  const float* B1 = fb1 + t*H2; const float* B2 = fb2 + t*HM;
  const float* W1  = fw1 + t*H1*H2;
  const float* W1T = ws + WS_FW1T + t*H2*H1;
  const float* W2T = ws + WS_FW2T + t*HM*H2;

  for(int i=s;i<HM*4;i+=128) RG4[i] = ws[WS_RGB + (size_t)bid*(HM*4) + i];
  __syncthreads();

  const float* p = ws + WS_P + (size_t)bid*GF;
  for(int i=s;i<GF;i+=128){
    int m=i>>4, a=i&15;
    float4 rm = *(const float4*)&RG4[m*4];
    float4 ra = *(const float4*)&RG4[a*4];
    float gv = rm.x*ra.x + rm.y*ra.y + rm.z*ra.z + rm.w*ra.w;
    float yv = (gv-mu)*inv_sd;
    dgb[m*17+a] = (p[i]-c1)*inv_sd - yv*c2;
  }
  __syncthreads();
  if(s < HM){
    const int m = s;
    float a0=0,b0=0,c0=0,d0=0;
#pragma unroll
    for(int a=0;a<AX;a++){
      float d = dgb[m*17+a];
      float4 r = *(const float4*)&RG4[a*4];
      a0 += d*r.x; b0 += d*r.y; c0 += d*r.z; d0 += d*r.w;
    }
    if(m<AX){
      for(int mp=0;mp<HM;mp++){
        float d = dgb[mp*17+m];
        float4 r = *(const float4*)&RG4[mp*4];
        a0 += d*r.x; b0 += d*r.y; c0 += d*r.z; d0 += d*r.w;
      }
    }
    *(float4*)&dRG4[m*4] = make_float4(a0,b0,c0,d0);
  }
  __syncthreads();

  float4 R4 = *(const float4*)&sym[(size_t)bid*NSEL*4 + s*4];
  float rn0 = (R4.x-avg_s)*inv_ss, rn1 = R4.y*inv_sx, rn2 = R4.z*inv_sx, rn3 = R4.w*inv_sx;

  float a1[H1];
#pragma unroll
  for(int kk=0;kk<H1;kk++) a1[kk] = ftanh(rn0*W0[kk] + B0[kk]);
  float a2[H2];
#pragma unroll
  for(int j=0;j<H2;j++){
    float acc = B1[j];
    const float* wr = W1T + j*H1;
#pragma unroll
    for(int kk=0;kk<H1;kk++) acc += a1[kk]*wr[kk];
    a2[j] = ftanh(acc);
  }

  float dz2a[H2];
#pragma unroll
  for(int j=0;j<H2;j++) dz2a[j]=0.f;
  float drn0=0,drn1=0,drn2=0,drn3=0;
  for(int m=0;m<HM;m+=4){
    const float* wr0 = W2T + m*H2; const float* wr1 = wr0 + H2;
    const float* wr2 = wr1 + H2;  const float* wr3 = wr2 + H2;
    float acc0 = B2[m], acc1 = B2[m+1], acc2 = B2[m+2], acc3 = B2[m+3];
#pragma unroll
    for(int j=0;j<H2;j++){
      float aj = a2[j];
      acc0 += aj*wr0[j]; acc1 += aj*wr1[j]; acc2 += aj*wr2[j]; acc3 += aj*wr3[j];
    }
    float g0 = ftanh(acc0), g1 = ftanh(acc1), g2 = ftanh(acc2), g3 = ftanh(acc3);
    float4 d0 = *(const float4*)&dRG4[m*4];
    float4 d1 = *(const float4*)&dRG4[(m+1)*4];
    float4 d2 = *(const float4*)&dRG4[(m+2)*4];
    float4 d3 = *(const float4*)&dRG4[(m+3)*4];
    drn0 += d0.x*g0 + d1.x*g1 + d2.x*g2 + d3.x*g3;
    drn1 += d0.y*g0 + d1.y*g1 + d2.y*g2 + d3.y*g3;
    drn2 += d0.z*g0 + d1.z*g1 + d2.z*g2 + d3.z*g3;
    drn3 += d0.w*g0 + d1.w*g1 + d2.w*g2 + d3.w*g3;
    float dz30 = (d0.x*rn0 + d0.y*rn1 + d0.z*rn2 + d0.w*rn3)*(1.f-g0*g0);
    float dz31 = (d1.x*rn0 + d1.y*rn1 + d1.z*rn2 + d1.w*rn3)*(1.f-g1*g1);
    float dz32 = (d2.x*rn0 + d2.y*rn1 + d2.z*rn2 + d2.w*rn3)*(1.f-g2*g2);
    float dz33 = (d3.x*rn0 + d3.y*rn1 + d3.z*rn2 + d3.w*rn3)*(1.f-g3*g3);
#pragma unroll
    for(int j=0;j<H2;j++) dz2a[j] += dz30*wr0[j] + dz31*wr1[j] + dz32*wr2[j] + dz33*wr3[j];
  }
#pragma unroll
  for(int j=0;j<H2;j++){ float av=a2[j]; dz2a[j] *= (1.f-av*av); }
  float dsacc=0.f;
#pragma unroll
  for(int kk=0;kk<H1;kk++){
    const float* wr = W1 + kk*H2;
    float acc=0.f;
#pragma unroll
    for(int j=0;j<H2;j++) acc += dz2a[j]*wr[j];
    float av=a1[kk];
    dsacc += acc*(1.f-av*av)*W0[kk];
  }
  drn0 += dsacc;
  float w0 = drn0*inv_ss, w1 = drn1*inv_sx, w2 = drn2*inv_sx, w3 = drn3*inv_sx;
  float4 X = *(const float4*)&dxp[(size_t)bid*NSEL*4 + s*4];
  float4 Y = *(const float4*)&dyp[(size_t)bid*NSEL*4 + s*4];
  float4 Z = *(const float4*)&dzp[(size_t)bid*NSEL*4 + s*4];
  float fx = w0*X.x + w1*X.y + w2*X.z + w3*X.w;
  float fy = w0*Y.x + w1*Y.y + w2*Y.z + w3*Y.w;
  float fz = w0*Z.x + w1*Z.y + w2*Z.z + w3*Z.w;
  fx = wave_sum(fx); fy = wave_sum(fy); fz = wave_sum(fz);
  __syncthreads();
  if((s&63)==0){ int w=s>>6; red[w*3+0]=fx; red[w*3+1]=fy; red[w*3+2]=fz; }
  __syncthreads();
  if(s==0){
    float* F = out + 4 + (size_t)bid*3;
    F[0] = -(red[0]+red[3]);
    F[1] = -(red[1]+red[4]);
    F[2] = -(red[2]+red[5]);
  }
}

__global__ void k_write_E(const float* __restrict__ ws, float* __restrict__ out){
  __shared__ float red[8];
  const int b = blockIdx.x;
  const float* e = ws + WS_EBUF + b*NATOM;
  float sv=0;
  for(int i=threadIdx.x;i<NATOM;i+=256) sv+=e[i];
  sv = block_sum4(sv, red);
  if(threadIdx.x==0) out[b]=sv;
}

extern "C" void kernel_launch(void* const* d_in, const int* in_sizes, int n_in,
                              void* d_out, int out_size, void* d_ws, size_t ws_size,
                              hipStream_t stream) {
  const float* sym = (const float*)d_in[0];
  const float* dxp = (const float*)d_in[1];
  const float* dyp = (const float*)d_in[2];
  const float* dzp = (const float*)d_in[3];
  const int*   types=(const int*)d_in[4];
  const float* fw0=(const float*)d_in[5];
  const float* fb0=(const float*)d_in[6];
  const float* fw1=(const float*)d_in[7];
  const float* fb1=(const float*)d_in[8];
  const float* fw2=(const float*)d_in[9];
  const float* fb2=(const float*)d_in[10];
  const float* gw0=(const float*)d_in[11];
  const float* gb0=(const float*)d_in[12];
  const float* gw1=(const float*)d_in[13];
  const float* gb1=(const float*)d_in[14];
  const float* gw2=(const float*)d_in[15];
  const float* gb2=(const float*)d_in[16];
  const float* gwo=(const float*)d_in[17];
  const float* gbo=(const float*)d_in[18];
  float* ws = (float*)d_ws;
  float* out = (float*)d_out;

  const size_t need_bytes = (size_t)WS_END * 4;
  const int storeGT = (ws_size >= need_bytes) ? 1 : 0;

  hipMemsetAsync(d_ws, 0, 1024, stream);
  hipMemsetAsync((char*)d_ws + (size_t)WS_IDX*4, 0xFF, (size_t)NBATCH*1152*4, stream);

  k_transpose<<<1024,256,0,stream>>>(gw0,gw1,gw2,fw1,fw2,ws);
  if(storeGT) k_packf<<<64,256,0,stream>>>(fw1,fw2,ws);
  k_stats<<<dim3(16,NBATCH),256,0,stream>>>(sym,types,ws);
  k_fin_stats<<<1,64,0,stream>>>(ws);
  k_index<<<NBATCH,256,0,stream>>>(types,ws);

  if(storeGT){
    const int lds_fwdm = 48224;
    hipFuncSetAttribute((const void*)k_fwdm, hipFuncAttributeMaxDynamicSharedMemorySize, lds_fwdm);
    k_fwdm<<<NBATCH*NATOM,128,lds_fwdm,stream>>>(sym,types,fw0,fb0,fb1,fb2,ws);
  } else {
    k_fwd<<<NBATCH*NATOM,128,0,stream>>>(sym,types,fw0,fb0,fb1,fb2,ws);
  }
  k_fin_musd<<<1,64,0,stream>>>(ws);

  const int lds_fitm = 3*64*264*2;   // 101376 B
  hipFuncSetAttribute((const void*)k_fitm, hipFuncAttributeMaxDynamicSharedMemorySize, lds_fitm);
  k_fitm<<<NBATCH*NGRP64,256,lds_fitm,stream>>>(gb0,gb1,gb2,gwo,gbo,ws);

  const int lds_pm = 64*264*2;       // 33792 B
  hipFuncSetAttribute((const void*)k_pm, hipFuncAttributeMaxDynamicSharedMemorySize, lds_pm);
  k_pm<<<NBATCH*NGRP64*PCH,256,lds_pm,stream>>>(ws);

  if(storeGT){
    const int lds_bwdm = 79616;
    hipFuncSetAttribute((const void*)k_bwdm2, hipFuncAttributeMaxDynamicSharedMemorySize, lds_bwdm);
    k_bwdm2<<<NBATCH*NATOM,128,lds_bwdm,stream>>>(sym,dxp,dyp,dzp,types,fw0,fb0,fb1,ws,out);
  } else {
    k_bwd0<<<NBATCH*NATOM,128,0,stream>>>(sym,dxp,dyp,dzp,types,fw0,fb0,fw1,fb1,fb2,ws,out);
  }

  k_write_E<<<NBATCH,256,0,stream>>>(ws,out);
}

// Round 23
// 704.483 us; speedup vs baseline: 1.1275x; 1.0540x over previous
//
#include <hip/hip_runtime.h>

#define NBATCH 4
#define NATOM 1024
#define NSEL 128
#define H1 25
#define H2 50
#define HM 100
#define AX 16
#define GF 1600
#define FI 240
#define NT 2
#define NGRP64 18   // 64-atom type-pure groups per batch (1152/64)
#define PCH 5       // N-chunks for k_pm (20 ntiles each)

// ---- workspace layout (float/uint offsets) ----
#define WS_STATS_RAW 0
#define WS_STATS_FIN 64      // [avg_s, inv_ss, inv_sx, cntf, rawcnt]
#define WS_MUSD_RAW 128
#define WS_MUSD_FIN 144
#define WS_S_RAW 176
#define WS_CTR 192
#define WS_EBUF 256
#define WS_IDX (WS_EBUF + NBATCH*NATOM)                  // ints, per-batch type-sorted, 1152/batch
#define WS_G (WS_IDX + NBATCH*1152)
#define WS_P (WS_G + (size_t)NBATCH*NATOM*GF)
// MFMA B-fragment packs for fit net:
#define WS_BP0  (WS_P + (size_t)NBATCH*NATOM*GF)         // [t][15][50][64][4]  L0 (gw0)
#define WS_BP1  (WS_BP0 + (size_t)NT*15*50*256)          // [t][15][8][64][4]   L1 (gw1)
#define WS_BP2  (WS_BP1 + (size_t)NT*15*8*256)           // L2 (gw2)
#define WS_BPT2 (WS_BP2 + (size_t)NT*15*8*256)           // dz2 (gw2^T)
#define WS_BPT1 (WS_BPT2 + (size_t)NT*15*8*256)          // dz1 (gw1^T)
#define WS_BPT0 (WS_BPT1 + (size_t)NT*15*8*256)          // [t][100][8][64][4]  p (gw0^T)
#define WS_FW1T (WS_BPT0 + (size_t)NT*100*8*256)         // fp32 filter transposes
#define WS_FW2T (WS_FW1T + (size_t)NT*H2*H1)
#define WS_RGB (WS_FW2T + (size_t)NT*HM*H2)              // RG store: NBATCH*NATOM*400
#define WS_GTB (WS_RGB + (size_t)NBATCH*NATOM*HM*4)      // GT-packed bf16 G: [atom][HM/2][NSEL]
#define WS_GTB_UNITS ((size_t)NBATCH*NATOM*(HM/2)*NSEL)
// filter-net B-frag packs:
#define WS_BF1B  (WS_GTB + WS_GTB_UNITS)                 // [t][4nt][64][4]      a2 fwd (fw1)
#define WS_BW2TB (WS_BF1B + (size_t)NT*1024)             // [t][4nt][4ks][64][4] dz2 (fw2^T)
#define WS_BW1TB (WS_BW2TB + (size_t)NT*4096)            // [t][2nt][2ks][64][4] dz1 (fw1^T)
#define WS_BF2B  (WS_BW1TB + (size_t)NT*1024)            // [t][7nt][2ks][64][4] G fwd (fw2)
#define WS_DZ1  (WS_BF2B + (size_t)NT*3584)              // dz1 frag images: [72 groups][8448 uints]
#define WS_END  (WS_DZ1 + (size_t)NBATCH*NGRP64*8448)

#define GSTR 108   // ushort stride for G in LDS

typedef __attribute__((ext_vector_type(8))) short bf16x8;
typedef __attribute__((ext_vector_type(4))) float f32x4;
typedef __attribute__((address_space(1))) const unsigned GU;
typedef __attribute__((address_space(3))) unsigned LU;

__device__ __forceinline__ float ftanh(float x){
  float e = __expf(2.0f*x);
  return 1.0f - 2.0f/(e+1.0f);
}
__device__ __forceinline__ unsigned short f2bf(float x){
  unsigned b=__float_as_uint(x); b += 0x7FFF + ((b>>16)&1); return (unsigned short)(b>>16);
}
__device__ __forceinline__ float bf2f(unsigned short h){ return __uint_as_float(((unsigned)h)<<16); }
__device__ __forceinline__ float bflo(unsigned u){ return __uint_as_float(u<<16); }
__device__ __forceinline__ float bfhi(unsigned u){ return __uint_as_float(u & 0xFFFF0000u); }
__device__ __forceinline__ unsigned packbf(float a, float b){
  return (unsigned)f2bf(a) | ((unsigned)f2bf(b)<<16);
}

__device__ __forceinline__ float wave_sum(float v){
#pragma unroll
  for(int o=32;o>0;o>>=1) v += __shfl_down(v,o,64);
  return v;
}
__device__ __forceinline__ float block_sum2(float v, float* red){
  v = wave_sum(v);
  __syncthreads();
  if((threadIdx.x&63)==0) red[threadIdx.x>>6]=v;
  __syncthreads();
  return red[0]+red[1];
}
__device__ __forceinline__ float block_sum4(float v, float* red){
  v = wave_sum(v);
  __syncthreads();
  if((threadIdx.x&63)==0) red[threadIdx.x>>6]=v;
  __syncthreads();
  return red[0]+red[1]+red[2]+red[3];
}

// ---- pack fit-net MFMA B-fragments (bf16) + fp32 filter transposes ----
__global__ void __launch_bounds__(256) k_transpose(const float* __restrict__ gw0,
    const float* __restrict__ gw1, const float* __restrict__ gw2,
    const float* __restrict__ fw1, const float* __restrict__ fw2, float* __restrict__ ws){
  const int cB0 = NT*15*50*256;
  const int cB1 = NT*15*8*256;
  const int cT0 = NT*100*8*256;
  const int c6 = NT*H2*H1, c7 = NT*HM*H2;
  const int total = cB0 + 4*cB1 + cT0 + c6 + c7;
  unsigned* wsu = (unsigned*)ws;
  for(int i = blockIdx.x*blockDim.x + threadIdx.x; i < total; i += gridDim.x*blockDim.x){
    if(i < cB0 + 4*cB1 + cT0){
      int base, NKs; const float* W; int KK; int mode; int t;
      int ii = i;
      if(ii < cB0){ base=WS_BP0; NKs=50; KK=1600; mode=0; t = ii/(15*50*256); ii -= t*(15*50*256); W = gw0 + (size_t)t*GF*FI; }
      else if(ii < cB0+cB1){ ii-=cB0; base=WS_BP1; NKs=8; KK=240; mode=0; t = ii/(15*8*256); ii -= t*(15*8*256); W = gw1 + t*FI*FI; }
      else if(ii < cB0+2*cB1){ ii-=cB0+cB1; base=WS_BP2; NKs=8; KK=240; mode=0; t = ii/(15*8*256); ii -= t*(15*8*256); W = gw2 + t*FI*FI; }
      else if(ii < cB0+3*cB1){ ii-=cB0+2*cB1; base=WS_BPT2; NKs=8; KK=240; mode=1; t = ii/(15*8*256); ii -= t*(15*8*256); W = gw2 + t*FI*FI; }
      else if(ii < cB0+4*cB1){ ii-=cB0+3*cB1; base=WS_BPT1; NKs=8; KK=240; mode=1; t = ii/(15*8*256); ii -= t*(15*8*256); W = gw1 + t*FI*FI; }
      else { ii-=cB0+4*cB1; base=WS_BPT0; NKs=8; KK=240; mode=2; t = ii/(100*8*256); ii -= t*(100*8*256); W = gw0 + (size_t)t*GF*FI; }
      int d = ii & 3;
      int lane = (ii>>2) & 63;
      int rem = ii >> 8;
      int ks = rem % NKs;
      int ntile = rem / NKs;
      int n = ntile*16 + (lane&15);
      int k0 = ks*32 + ((lane>>4)&3)*8 + 2*d;
      float v0, v1;
      if(mode==0){
        v0 = (k0   < KK) ? W[(size_t)(k0  )*FI + n] : 0.f;
        v1 = (k0+1 < KK) ? W[(size_t)(k0+1)*FI + n] : 0.f;
      } else if(mode==1){
        v0 = (k0   < KK) ? W[n*FI + k0  ] : 0.f;
        v1 = (k0+1 < KK) ? W[n*FI + k0+1] : 0.f;
      } else {
        v0 = (k0   < KK) ? W[(size_t)n*FI + k0  ] : 0.f;
        v1 = (k0+1 < KK) ? W[(size_t)n*FI + k0+1] : 0.f;
      }
      int telems = (base==WS_BP0) ? 15*50*256 : (base==WS_BPT0 ? 100*8*256 : 15*8*256);
      wsu[base + (size_t)t*telems + ii] = packbf(v0, v1);
    } else if(i < cB0 + 4*cB1 + cT0 + c6){
      int ii = i - (cB0+4*cB1+cT0); int t = ii/(H2*H1); int rem = ii - t*(H2*H1);
      int j = rem/H1; int k = rem - j*H1;
      ws[WS_FW1T + ii] = fw1[t*H1*H2 + k*H2 + j];
    } else {
      int ii = i - (cB0+4*cB1+cT0+c6); int t = ii/(HM*H2); int rem = ii - t*(HM*H2);
      int m = rem/H2; int j = rem - m*H2;
      ws[WS_FW2T + ii] = fw2[t*H2*HM + j*HM + m];
    }
  }
}

// ---- pack filter-net B-fragments for k_bwdm2 / k_fwdm ----
__global__ void __launch_bounds__(256) k_packf(const float* __restrict__ fw1,
    const float* __restrict__ fw2, float* __restrict__ ws){
  unsigned* wsu = (unsigned*)ws;
  const int c1 = NT*1024, c2 = NT*4096, c3 = NT*1024, c4 = NT*3584;
  const int total = c1 + c2 + c3 + c4;
  for(int i = blockIdx.x*blockDim.x + threadIdx.x; i < total; i += gridDim.x*blockDim.x){
    if(i < c1){                      // BF1
      int t = i/1024; int ii = i - t*1024;
      int nt = ii>>8; int lane = (ii>>2)&63; int d = ii&3;
      int n = nt*16 + (lane&15);
      int k0 = ((lane>>4)&3)*8 + 2*d;
      float v0 = (k0   < H1 && n < H2) ? fw1[t*H1*H2 + (k0  )*H2 + n] : 0.f;
      float v1 = (k0+1 < H1 && n < H2) ? fw1[t*H1*H2 + (k0+1)*H2 + n] : 0.f;
      wsu[WS_BF1B + i] = packbf(v0, v1);
    } else if(i < c1 + c2){          // BW2T
      int ii = i - c1; int t = ii/4096; ii -= t*4096;
      int nt = ii>>10; int ks = (ii>>8)&3; int lane = (ii>>2)&63; int d = ii&3;
      int n = nt*16 + (lane&15);
      int k0 = ks*32 + ((lane>>4)&3)*8 + 2*d;
      float v0 = (k0   < HM && n < H2) ? fw2[t*H2*HM + n*HM + k0  ] : 0.f;
      float v1 = (k0+1 < HM && n < H2) ? fw2[t*H2*HM + n*HM + k0+1] : 0.f;
      wsu[WS_BW2TB + ii + t*4096] = packbf(v0, v1);
    } else if(i < c1 + c2 + c3){     // BW1T
      int ii = i - c1 - c2; int t = ii/1024; ii -= t*1024;
      int nt = ii>>9; int ks = (ii>>8)&1; int lane = (ii>>2)&63; int d = ii&3;
      int n = nt*16 + (lane&15);
      int k0 = ks*32 + ((lane>>4)&3)*8 + 2*d;
      float v0 = (k0   < H2 && n < H1) ? fw1[t*H1*H2 + n*H2 + k0  ] : 0.f;
      float v1 = (k0+1 < H2 && n < H1) ? fw1[t*H1*H2 + n*H2 + k0+1] : 0.f;
      wsu[WS_BW1TB + ii + t*1024] = packbf(v0, v1);
    } else {                         // BF2
      int ii = i - c1 - c2 - c3; int t = ii/3584; ii -= t*3584;
      int nt = ii>>9; int ks = (ii>>8)&1; int lane = (ii>>2)&63; int d = ii&3;
      int n = nt*16 + (lane&15);
      int k0 = ks*32 + ((lane>>4)&3)*8 + 2*d;
      float v0 = (k0   < H2 && n < HM) ? fw2[t*H2*HM + (k0  )*HM + n] : 0.f;
      float v1 = (k0+1 < H2 && n < HM) ? fw2[t*H2*HM + (k0+1)*HM + n] : 0.f;
      wsu[WS_BF2B + ii + t*3584] = packbf(v0, v1);
    }
  }
}

__global__ void __launch_bounds__(256) k_stats(const float* __restrict__ sym,
    const int* __restrict__ types, float* __restrict__ ws){
  const int b = blockIdx.y;
  const int n0 = blockIdx.x * 64;
  const float* R = sym + ((size_t)b*NATOM + n0)*NSEL*4;
  const int* ty = types + b*NATOM;
  float ss0=0,ss20=0,xs0=0,xs20=0,ss1=0,ss21=0,xs1=0,xs21=0,c0=0,c1=0;
  for(int idx=threadIdx.x; idx<64*NSEL*4; idx+=256){
    int a = idx >> 9;
    int t = ty[n0+a];
    float v = R[idx];
    bool iss = (idx&3)==0;
    if(t==0){ if(iss){ss0+=v;ss20+=v*v;} else {xs0+=v;xs20+=v*v;} }
    else    { if(iss){ss1+=v;ss21+=v*v;} else {xs1+=v;xs21+=v*v;} }
  }
  if(threadIdx.x<64){ if(ty[n0+threadIdx.x]==0) c0=1.f; else c1=1.f; }
  ss0=wave_sum(ss0); ss20=wave_sum(ss20); xs0=wave_sum(xs0); xs20=wave_sum(xs20); c0=wave_sum(c0);
  ss1=wave_sum(ss1); ss21=wave_sum(ss21); xs1=wave_sum(xs1); xs21=wave_sum(xs21); c1=wave_sum(c1);
  if((threadIdx.x&63)==0){
    float* r0 = ws + WS_STATS_RAW + (b*2+0)*8;
    float* r1 = ws + WS_STATS_RAW + (b*2+1)*8;
    atomicAdd(r0+0,c0); atomicAdd(r0+1,ss0); atomicAdd(r0+2,ss20); atomicAdd(r0+3,xs0); atomicAdd(r0+4,xs20);
    atomicAdd(r1+0,c1); atomicAdd(r1+1,ss1); atomicAdd(r1+2,ss21); atomicAdd(r1+3,xs1); atomicAdd(r1+4,xs21);
  }
}

__global__ void k_fin_stats(float* ws){
  int i = threadIdx.x;
  if(i<8){
    float* raw = ws + WS_STATS_RAW + i*8;
    float cntf = fmaxf(raw[0], 1.f);
    float ns = cntf * (float)NSEL;
    float s_avg = raw[1]/ns, s_avg2 = raw[2]/ns;
    float x_avg = raw[3]/(ns*3.f), x_avg2 = raw[4]/(ns*3.f);
    float std_s = sqrtf(fmaxf(s_avg2 - s_avg*s_avg, 0.f)) + 1e-8f;
    float std_x = sqrtf(fmaxf(x_avg2 - x_avg*x_avg, 0.f)) + 1e-8f;
    float* fin = ws + WS_STATS_FIN + i*8;
    fin[0]=s_avg; fin[1]=1.f/std_s; fin[2]=1.f/std_x; fin[3]=cntf; fin[4]=raw[0];
  }
}

__global__ void k_index(const int* __restrict__ types, float* __restrict__ ws){
  int b = blockIdx.x;
  int rc0 = (int)ws[WS_STATS_FIN + (b*2)*8 + 4];
  int pad0 = (rc0+63)&~63;
  int* ctr = (int*)ws + WS_CTR;
  int* idx = (int*)ws + WS_IDX;
  for(int n=threadIdx.x;n<NATOM;n+=256){
    int t = types[b*NATOM+n];
    int pos = atomicAdd(&ctr[b*2+t],1);
    idx[b*1152 + (t ? pad0+pos : pos)] = n;
  }
}

// ---- descriptor forward via MFMA filter layers (storeGT path) ----
__global__ void __launch_bounds__(128) k_fwdm(const float* __restrict__ sym, const int* __restrict__ types,
    const float* __restrict__ fw0,const float* __restrict__ fb0,
    const float* __restrict__ fb1,const float* __restrict__ fb2,
    float* __restrict__ ws){
  extern __shared__ char fraw[];
  float* Rn4 = (float*)fraw;                              // 512 f -> 2048
  float* RG4 = (float*)(fraw + 2048);                     // 400 f -> 3648
  float* red = (float*)(fraw + 3648);                     // 8 f  -> 3680
  unsigned short* a2F = (unsigned short*)(fraw + 3680);   // [128][66] -> 20576
  unsigned* a2Fu = (unsigned*)(fraw + 3680);              // stride 33 uints
  unsigned* a1L = (unsigned*)(fraw + 20576);              // [128][17] uints (aliases Gl)
  unsigned short* Gl = (unsigned short*)(fraw + 20576);   // [128][GSTR] ushort -> 48224

  const int bid = blockIdx.x;
  const int b = bid >> 10;
  int t = types[bid];
  t = __builtin_amdgcn_readfirstlane(t);
  const float* fin = ws + WS_STATS_FIN + (b*2+t)*8;
  const float avg_s = fin[0], inv_ss = fin[1], inv_sx = fin[2];
  const int s = threadIdx.x;
  const int wave = s>>6, lane = s&63, lw = lane&15, lg = lane>>4;

  const float* W0 = fw0 + t*H1; const float* B0 = fb0 + t*H1;
  const float* B1 = fb1 + t*H2; const float* B2 = fb2 + t*HM;
  const unsigned* wsu = (const unsigned*)ws;
  const bf16x8* BF1 = (const bf16x8*)(wsu + WS_BF1B) + t*4*64;
  const bf16x8* BF2 = (const bf16x8*)(wsu + WS_BF2B) + t*14*64;

  float4 R4 = *(const float4*)&sym[(size_t)bid*NSEL*4 + s*4];
  float rn0 = (R4.x-avg_s)*inv_ss, rn1 = R4.y*inv_sx, rn2 = R4.z*inv_sx, rn3 = R4.w*inv_sx;
  *(float4*)&Rn4[s*4] = make_float4(rn0,rn1,rn2,rn3);

  {
    float a1r[H1];
#pragma unroll
    for(int kk=0;kk<H1;kk++) a1r[kk] = ftanh(rn0*W0[kk] + B0[kk]);
    unsigned* rw = a1L + s*17;
#pragma unroll
    for(int q=0;q<12;q++) rw[q] = packbf(a1r[2*q], a1r[2*q+1]);
    rw[12] = packbf(a1r[24], 0.f);
    rw[13]=0; rw[14]=0; rw[15]=0; rw[16]=0;
  }
  __syncthreads();

  const f32x4 fz = {0.f,0.f,0.f,0.f};
  for(int nt=0;nt<4;nt++){
    f32x4 acc[4];
#pragma unroll
    for(int mt=0;mt<4;mt++){
      int MT = wave*4 + mt;
      bf16x8 af = *(const bf16x8*)&a1L[(MT*16+lw)*17 + lg*4];
      acc[mt] = __builtin_amdgcn_mfma_f32_16x16x32_bf16(af, BF1[nt*64+lane], fz, 0,0,0);
    }
    int col = nt*16 + lw;
    float bias = (col<H2) ? B1[col] : 0.f;
#pragma unroll
    for(int mt=0;mt<4;mt++)
#pragma unroll
      for(int r=0;r<4;r++){
        int rw = (wave*4+mt)*16 + lg*4 + r;
        float v = (col<H2) ? ftanh(acc[mt][r] + bias) : 0.f;
        a2F[rw*66 + col] = f2bf(v);
      }
  }
  __syncthreads();
  for(int nt=0;nt<7;nt++){
    f32x4 acc[4];
#pragma unroll
    for(int mt=0;mt<4;mt++) acc[mt] = fz;
    for(int ks=0;ks<2;ks++){
#pragma unroll
      for(int mt=0;mt<4;mt++){
        int MT = wave*4 + mt;
        bf16x8 af = *(const bf16x8*)&a2Fu[(MT*16+lw)*33 + ks*16 + lg*4];
        acc[mt] = __builtin_amdgcn_mfma_f32_16x16x32_bf16(af, BF2[(nt*2+ks)*64+lane], acc[mt], 0,0,0);
      }
    }
    int col = nt*16 + lw;
    if(col < HM){
      float bias = B2[col];
#pragma unroll
      for(int mt=0;mt<4;mt++)
#pragma unroll
        for(int r=0;r<4;r++){
          int rw = (wave*4+mt)*16 + lg*4 + r;
          Gl[rw*GSTR + col] = f2bf(ftanh(acc[mt][r] + bias));
        }
    }
  }
  __syncthreads();
  if(s < HM){
    const int m = s;
    float a0=0,b0=0,c0=0,d0=0;
    for(int sn=0;sn<NSEL;sn++){
      float4 rn = *(const float4*)&Rn4[sn*4];
      float g = bf2f(Gl[sn*GSTR+m]);
      a0 += rn.x*g; b0 += rn.y*g; c0 += rn.z*g; d0 += rn.w*g;
    }
    *(float4*)&RG4[m*4] = make_float4(a0,b0,c0,d0);
  }
  __syncthreads();
  for(int i=s;i<HM*4;i+=128) ws[WS_RGB + (size_t)bid*(HM*4) + i] = RG4[i];
  {
    unsigned* GT = (unsigned*)ws + WS_GTB + (size_t)bid*((HM/2)*NSEL);
    for(int i=s;i<(HM/2)*NSEL;i+=128){
      int mp = i >> 7, ss = i & 127;
      GT[i] = *(const unsigned*)&Gl[ss*GSTR + 2*mp];
    }
  }
  float lsum=0,lsum2=0;
  float* gout = ws + WS_G + (size_t)bid*GF;
  for(int i=s;i<GF;i+=128){
    int m=i>>4, a=i&15;
    float4 rm = *(const float4*)&RG4[m*4];
    float4 ra = *(const float4*)&RG4[a*4];
    float gv = rm.x*ra.x + rm.y*ra.y + rm.z*ra.z + rm.w*ra.w;
    gout[i]=gv; lsum+=gv; lsum2+=gv*gv;
  }
  lsum = block_sum2(lsum, red);
  lsum2 = block_sum2(lsum2, red);
  if(s==0){
    atomicAdd(&ws[WS_MUSD_RAW + (b*2+t)*2 + 0], lsum);
    atomicAdd(&ws[WS_MUSD_RAW + (b*2+t)*2 + 1], lsum2);
  }
}

// ---- scalar descriptor forward (fallback) ----
__global__ void __launch_bounds__(128) k_fwd(const float* __restrict__ sym, const int* __restrict__ types,
    const float* __restrict__ fw0,const float* __restrict__ fb0,
    const float* __restrict__ fb1,const float* __restrict__ fb2,
    float* __restrict__ ws){
  __shared__ float Rn4[NSEL*4];
  __shared__ unsigned short Gl[NSEL*GSTR];
  __shared__ float RG4[HM*4];
  __shared__ float red[8];

  const int bid = blockIdx.x;
  const int b = bid >> 10;
  int t = types[bid];
  t = __builtin_amdgcn_readfirstlane(t);
  const float* fin = ws + WS_STATS_FIN + (b*2+t)*8;
  const float avg_s = fin[0], inv_ss = fin[1], inv_sx = fin[2];
  const int s = threadIdx.x;

  const float* W0 = fw0 + t*H1; const float* B0 = fb0 + t*H1;
  const float* B1 = fb1 + t*H2; const float* B2 = fb2 + t*HM;
  const float* W1T = ws + WS_FW1T + t*H2*H1;
  const float* W2T = ws + WS_FW2T + t*HM*H2;

  float4 R4 = *(const float4*)&sym[(size_t)bid*NSEL*4 + s*4];
  float rn0 = (R4.x-avg_s)*inv_ss, rn1 = R4.y*inv_sx, rn2 = R4.z*inv_sx, rn3 = R4.w*inv_sx;
  *(float4*)&Rn4[s*4] = make_float4(rn0,rn1,rn2,rn3);

  float a1[H1];
#pragma unroll
  for(int k=0;k<H1;k++) a1[k] = ftanh(rn0*W0[k] + B0[k]);
  float a2[H2];
#pragma unroll
  for(int j=0;j<H2;j++){
    float acc = B1[j];
    const float* wr = W1T + j*H1;
#pragma unroll
    for(int k=0;k<H1;k++) acc += a1[k]*wr[k];
    a2[j] = ftanh(acc);
  }
  for(int m=0;m<HM;m+=4){
    const float* wr0 = W2T + m*H2; const float* wr1 = wr0 + H2;
    const float* wr2 = wr1 + H2;  const float* wr3 = wr2 + H2;
    float acc0 = B2[m], acc1 = B2[m+1], acc2 = B2[m+2], acc3 = B2[m+3];
#pragma unroll
    for(int j=0;j<H2;j++){
      float aj = a2[j];
      acc0 += aj*wr0[j]; acc1 += aj*wr1[j]; acc2 += aj*wr2[j]; acc3 += aj*wr3[j];
    }
    unsigned u0 = (unsigned)f2bf(ftanh(acc0)) | ((unsigned)f2bf(ftanh(acc1))<<16);
    unsigned u1 = (unsigned)f2bf(ftanh(acc2)) | ((unsigned)f2bf(ftanh(acc3))<<16);
    *(unsigned*)&Gl[s*GSTR + m] = u0;
    *(unsigned*)&Gl[s*GSTR + m + 2] = u1;
  }
  __syncthreads();
  if(s < HM){
    const int m = s;
    float a0=0,b0=0,c0=0,d0=0;
    for(int sn=0;sn<NSEL;sn++){
      float4 rn = *(const float4*)&Rn4[sn*4];
      float g = bf2f(Gl[sn*GSTR+m]);
      a0 += rn.x*g; b0 += rn.y*g; c0 += rn.z*g; d0 += rn.w*g;
    }
    *(float4*)&RG4[m*4] = make_float4(a0,b0,c0,d0);
  }
  __syncthreads();
  for(int i=s;i<HM*4;i+=128) ws[WS_RGB + (size_t)bid*(HM*4) + i] = RG4[i];
  float lsum=0,lsum2=0;
  float* gout = ws + WS_G + (size_t)bid*GF;
  for(int i=s;i<GF;i+=128){
    int m=i>>4, a=i&15;
    float4 rm = *(const float4*)&RG4[m*4];
    float4 ra = *(const float4*)&RG4[a*4];
    float gv = rm.x*ra.x + rm.y*ra.y + rm.z*ra.z + rm.w*ra.w;
    gout[i]=gv; lsum+=gv; lsum2+=gv*gv;
  }
  lsum = block_sum2(lsum, red);
  lsum2 = block_sum2(lsum2, red);
  if(s==0){
    atomicAdd(&ws[WS_MUSD_RAW + (b*2+t)*2 + 0], lsum);
    atomicAdd(&ws[WS_MUSD_RAW + (b*2+t)*2 + 1], lsum2);
  }
}

__global__ void k_fin_musd(float* ws){
  int i=threadIdx.x;
  if(i<8){
    float cntf = ws[WS_STATS_FIN + i*8 + 3];
    float denom = cntf * (float)GF;
    float Sg = ws[WS_MUSD_RAW + i*2], Sg2 = ws[WS_MUSD_RAW + i*2+1];
    float mu = Sg/denom, mu2 = Sg2/denom;
    float var = fmaxf(mu2 - mu*mu, 0.f);
    float r = sqrtf(var); float sd = r + 1e-8f;
    float* mf = ws + WS_MUSD_FIN + i*4;
    mf[0]=mu; mf[1]=1.f/sd; mf[2]=r; mf[3]=sd;
  }
}

// ---- fitting net via MFMA: fwd+bwd through dz1; dz1 image stored for k_pm ----
__global__ void __launch_bounds__(256) k_fitm(
    const float* __restrict__ gb0,const float* __restrict__ gb1,
    const float* __restrict__ gb2,
    const float* __restrict__ gwo,const float* __restrict__ gbo,
    float* __restrict__ ws){
  extern __shared__ unsigned short lb[];
  unsigned short* h1S = lb;              // [64][264]
  unsigned short* h2S = lb + 16896;
  unsigned short* dzA = lb + 33792;

  const int b = blockIdx.x / NGRP64;
  const int grp = blockIdx.x - b*NGRP64;
  int rc0 = (int)ws[WS_STATS_FIN + (b*2)*8 + 4];
  int rc1 = (int)ws[WS_STATS_FIN + (b*2+1)*8 + 4];
  rc0 = __builtin_amdgcn_readfirstlane(rc0);
  rc1 = __builtin_amdgcn_readfirstlane(rc1);
  const int pad0 = (rc0+63)&~63;
  const int tend = pad0 + ((rc1+63)&~63);
  const int slot0 = grp*64;
  if(slot0 >= tend) return;
  const int t = (slot0 >= pad0) ? 1 : 0;

  const float* mf = ws + WS_MUSD_FIN + (b*2+t)*4;
  const float mu = mf[0], isd = mf[1];

  const int tid = threadIdx.x;
  const int wave = tid>>6, lane = tid&63;
  const int lw = lane&15, lg = lane>>4;
  const int mRowBase = wave*16 + lg*4;

  const int* idx = (const int*)ws + WS_IDX + b*1152;
  int arow = idx[slot0 + wave*16 + lw];
  int rowSafe = arow<0?0:arow;
  const float* yrowA = ws + WS_G + (size_t)(b*NATOM + rowSafe)*GF;
  int idC[4];
#pragma unroll
  for(int r=0;r<4;r++) idC[r] = idx[slot0 + wave*16 + lg*4 + r];

  const unsigned* wsu = (const unsigned*)ws;
  const bf16x8* BP0  = (const bf16x8*)(wsu + WS_BP0)  + (size_t)t*15*50*64;
  const bf16x8* BP1  = (const bf16x8*)(wsu + WS_BP1)  + t*15*8*64;
  const bf16x8* BP2  = (const bf16x8*)(wsu + WS_BP2)  + t*15*8*64;
  const bf16x8* BPT2 = (const bf16x8*)(wsu + WS_BPT2) + t*15*8*64;
  const bf16x8* BPT1 = (const bf16x8*)(wsu + WS_BPT1) + t*15*8*64;

  for(int i=tid;i<64*24;i+=256){
    int r = i/24, c = 240 + (i - (i/24)*24);
    h1S[r*264+c]=0; h2S[r*264+c]=0; dzA[r*264+c]=0;
  }

  f32x4 acc[15];
  const f32x4 fz = {0.f,0.f,0.f,0.f};
#pragma unroll
  for(int nt=0;nt<15;nt++) acc[nt] = fz;
  for(int ks=0;ks<50;ks++){
    float4 y0 = *(const float4*)(yrowA + ks*32 + lg*8);
    float4 y1 = *(const float4*)(yrowA + ks*32 + lg*8 + 4);
    union{ unsigned u[4]; bf16x8 v; } A;
    A.u[0]=packbf((y0.x-mu)*isd,(y0.y-mu)*isd); A.u[1]=packbf((y0.z-mu)*isd,(y0.w-mu)*isd);
    A.u[2]=packbf((y1.x-mu)*isd,(y1.y-mu)*isd); A.u[3]=packbf((y1.z-mu)*isd,(y1.w-mu)*isd);
#pragma unroll
    for(int nt=0;nt<15;nt++)
      acc[nt] = __builtin_amdgcn_mfma_f32_16x16x32_bf16(A.v, BP0[(nt*50+ks)*64+lane], acc[nt], 0,0,0);
  }
#pragma unroll
  for(int nt=0;nt<15;nt++){
    float bias = gb0[t*FI + nt*16 + lw];
#pragma unroll
    for(int r=0;r<4;r++){
      float h = ftanh(acc[nt][r] + bias);
      h1S[(mRowBase+r)*264 + nt*16 + lw] = f2bf(h);
    }
  }
  __syncthreads();
#pragma unroll
  for(int nt=0;nt<15;nt++) acc[nt] = fz;
  for(int ks=0;ks<8;ks++){
    bf16x8 a = *(const bf16x8*)&h1S[(wave*16+lw)*264 + ks*32 + lg*8];
#pragma unroll
    for(int nt=0;nt<15;nt++)
      acc[nt] = __builtin_amdgcn_mfma_f32_16x16x32_bf16(a, BP1[(nt*8+ks)*64+lane], acc[nt], 0,0,0);
  }
#pragma unroll
  for(int nt=0;nt<15;nt++){
    float bias = gb1[t*FI + nt*16 + lw];
#pragma unroll
    for(int r=0;r<4;r++){
      float h = ftanh(acc[nt][r] + bias);
      h2S[(mRowBase+r)*264 + nt*16 + lw] = f2bf(h);
    }
  }
  __syncthreads();
#pragma unroll
  for(int nt=0;nt<15;nt++) acc[nt] = fz;
  for(int ks=0;ks<8;ks++){
    bf16x8 a = *(const bf16x8*)&h2S[(wave*16+lw)*264 + ks*32 + lg*8];
#pragma unroll
    for(int nt=0;nt<15;nt++)
      acc[nt] = __builtin_amdgcn_mfma_f32_16x16x32_bf16(a, BP2[(nt*8+ks)*64+lane], acc[nt], 0,0,0);
  }
  float pe[4] = {0.f,0.f,0.f,0.f};
#pragma unroll
  for(int nt=0;nt<15;nt++){
    float bias = gb2[t*FI + nt*16 + lw];
    float wo = gwo[t*FI + nt*16 + lw];
#pragma unroll
    for(int r=0;r<4;r++){
      float h = ftanh(acc[nt][r] + bias);
      pe[r] += h*wo;
      float d3 = wo*(1.f - h*h);
      dzA[(mRowBase+r)*264 + nt*16 + lw] = f2bf(d3);
    }
  }
#pragma unroll
  for(int o=1;o<16;o<<=1){
#pragma unroll
    for(int r=0;r<4;r++) pe[r] += __shfl_xor(pe[r], o, 64);
  }
  if(lw==0){
#pragma unroll
    for(int r=0;r<4;r++) if(idC[r]>=0) ws[WS_EBUF + b*NATOM + idC[r]] = pe[r] + gbo[t];
  }
  __syncthreads();
#pragma unroll
  for(int nt=0;nt<15;nt++) acc[nt] = fz;
  for(int ks=0;ks<8;ks++){
    bf16x8 a = *(const bf16x8*)&dzA[(wave*16+lw)*264 + ks*32 + lg*8];
#pragma unroll
    for(int nt=0;nt<15;nt++)
      acc[nt] = __builtin_amdgcn_mfma_f32_16x16x32_bf16(a, BPT2[(nt*8+ks)*64+lane], acc[nt], 0,0,0);
  }
#pragma unroll
  for(int nt=0;nt<15;nt++){
#pragma unroll
    for(int r=0;r<4;r++){
      float h2 = bf2f(h2S[(mRowBase+r)*264 + nt*16 + lw]);
      acc[nt][r] *= (1.f - h2*h2);
    }
  }
  __syncthreads();
#pragma unroll
  for(int nt=0;nt<15;nt++){
#pragma unroll
    for(int r=0;r<4;r++) dzA[(mRowBase+r)*264 + nt*16 + lw] = f2bf(acc[nt][r]);
  }
  __syncthreads();
#pragma unroll
  for(int nt=0;nt<15;nt++) acc[nt] = fz;
  for(int ks=0;ks<8;ks++){
    bf16x8 a = *(const bf16x8*)&dzA[(wave*16+lw)*264 + ks*32 + lg*8];
#pragma unroll
    for(int nt=0;nt<15;nt++)
      acc[nt] = __builtin_amdgcn_mfma_f32_16x16x32_bf16(a, BPT1[(nt*8+ks)*64+lane], acc[nt], 0,0,0);
  }
#pragma unroll
  for(int nt=0;nt<15;nt++){
#pragma unroll
    for(int r=0;r<4;r++){
      float h1 = bf2f(h1S[(mRowBase+r)*264 + nt*16 + lw]);
      acc[nt][r] *= (1.f - h1*h1);
    }
  }
  __syncthreads();
#pragma unroll
  for(int nt=0;nt<15;nt++){
#pragma unroll
    for(int r=0;r<4;r++) dzA[(mRowBase+r)*264 + nt*16 + lw] = f2bf(acc[nt][r]);
  }
  __syncthreads();
  // store dz1 frag image for k_pm
  {
    unsigned* dzOut = (unsigned*)ws + WS_DZ1 + (size_t)blockIdx.x*8448;
    const unsigned* dzAu = (const unsigned*)dzA;
    for(int i=tid;i<8448;i+=256) dzOut[i] = dzAu[i];
  }
}

// ---- p = dz1 @ gw0^T, N-chunked across blocks (all-CU coverage) + S1/Sy ----
__global__ void __launch_bounds__(256) k_pm(float* __restrict__ ws){
  extern __shared__ unsigned short lb[];   // dzA image [64][264]
  unsigned short* dzA = lb;
  __shared__ float red[4];

  const int gid = blockIdx.x / PCH;
  const int chunk = blockIdx.x - gid*PCH;
  const int b = gid / NGRP64;
  const int grp = gid - b*NGRP64;
  int rc0 = (int)ws[WS_STATS_FIN + (b*2)*8 + 4];
  int rc1 = (int)ws[WS_STATS_FIN + (b*2+1)*8 + 4];
  rc0 = __builtin_amdgcn_readfirstlane(rc0);
  rc1 = __builtin_amdgcn_readfirstlane(rc1);
  const int pad0 = (rc0+63)&~63;
  const int tend = pad0 + ((rc1+63)&~63);
  const int slot0 = grp*64;
  if(slot0 >= tend) return;
  const int t = (slot0 >= pad0) ? 1 : 0;

  const float* mf = ws + WS_MUSD_FIN + (b*2+t)*4;
  const float mu = mf[0], isd = mf[1];
  const int tid = threadIdx.x;
  const int wave = tid>>6, lane = tid&63, lw = lane&15, lg = lane>>4;

  const int* idx = (const int*)ws + WS_IDX + b*1152;
  int idC[4];
#pragma unroll
  for(int r=0;r<4;r++) idC[r] = idx[slot0 + wave*16 + lg*4 + r];

  const unsigned* wsu = (const unsigned*)ws;
  const bf16x8* BPT0 = (const bf16x8*)(wsu + WS_BPT0) + (size_t)t*100*8*64;

  // load dz1 image
  {
    const unsigned* src = (const unsigned*)ws + WS_DZ1 + (size_t)gid*8448;
    unsigned* dst = (unsigned*)lb;
    for(int i=tid;i<8448;i+=256) dst[i] = src[i];
  }
  __syncthreads();

  const f32x4 fz = {0.f,0.f,0.f,0.f};
  const float* yG = ws + WS_G + (size_t)b*NATOM*GF;
  float* pP = ws + WS_P + (size_t)b*NATOM*GF;
  float s1t=0.f, syt=0.f;
  for(int sc=0;sc<2;sc++){
    int c0 = chunk*20 + sc*10;
    f32x4 pc[10];
#pragma unroll
    for(int j=0;j<10;j++) pc[j] = fz;
    for(int ks=0;ks<8;ks++){
      bf16x8 a = *(const bf16x8*)&dzA[(wave*16+lw)*264 + ks*32 + lg*8];
#pragma unroll
      for(int j=0;j<10;j++)
        pc[j] = __builtin_amdgcn_mfma_f32_16x16x32_bf16(a, BPT0[((c0+j)*8+ks)*64+lane], pc[j], 0,0,0);
    }
#pragma unroll
    for(int j=0;j<10;j++){
      int n = (c0+j)*16 + lw;
#pragma unroll
      for(int r=0;r<4;r++){
        if(idC[r]>=0){
          float pv = pc[j][r];
          size_t off = (size_t)idC[r]*GF + n;
          pP[off] = pv;
          s1t += pv;
          syt += pv * (yG[off]-mu)*isd;
        }
      }
    }
  }
  s1t = block_sum4(s1t, red);
  syt = block_sum4(syt, red);
  if(tid==0){
    atomicAdd(&ws[WS_S_RAW+(b*2+t)*2+0], s1t);
    atomicAdd(&ws[WS_S_RAW+(b*2+t)*2+1], syt);
  }
}

// ---- dgb -> dRG4 per atom at full occupancy; dRG4 overwrites the consumed p-row ----
__global__ void __launch_bounds__(128) k_dgb(const int* __restrict__ types, float* __restrict__ ws){
  __shared__ float RG4[HM*4];
  __shared__ float dgb[HM*17];
  const int bid = blockIdx.x;
  const int b = bid >> 10;
  int t = types[bid];
  t = __builtin_amdgcn_readfirstlane(t);
  const float* fin = ws + WS_STATS_FIN + (b*2+t)*8;
  const float cntf = fin[3];
  const float* mf = ws + WS_MUSD_FIN + (b*2+t)*4;
  const float mu=mf[0], inv_sd=mf[1], rr=mf[2];
  const float S1 = ws[WS_S_RAW + (b*2+t)*2 + 0];
  const float Sy = ws[WS_S_RAW + (b*2+t)*2 + 1];
  const float denom = cntf * (float)GF;
  const float c1 = S1/denom;
  const float c2 = (rr>0.f) ? (Sy/denom)/rr : 0.f;
  const int s = threadIdx.x;

  for(int i=s;i<HM*4;i+=128) RG4[i] = ws[WS_RGB + (size_t)bid*(HM*4) + i];
  __syncthreads();
  float* p = ws + WS_P + (size_t)bid*GF;
  for(int i=s;i<GF;i+=128){
    int m=i>>4, a=i&15;
    float4 rm = *(const float4*)&RG4[m*4];
    float4 ra = *(const float4*)&RG4[a*4];
    float gv = rm.x*ra.x + rm.y*ra.y + rm.z*ra.z + rm.w*ra.w;
    float yv = (gv-mu)*inv_sd;
    dgb[m*17+a] = (p[i]-c1)*inv_sd - yv*c2;
  }
  __syncthreads();   // all p reads done; dgb ready
  if(s < HM){
    const int m = s;
    float a0=0,b0=0,c0=0,d0=0;
#pragma unroll
    for(int a=0;a<AX;a++){
      float d = dgb[m*17+a];
      float4 r = *(const float4*)&RG4[a*4];
      a0 += d*r.x; b0 += d*r.y; c0 += d*r.z; d0 += d*r.w;
    }
    if(m<AX){
      for(int mp=0;mp<HM;mp++){
        float d = dgb[mp*17+m];
        float4 r = *(const float4*)&RG4[mp*4];
        a0 += d*r.x; b0 += d*r.y; c0 += d*r.z; d0 += d*r.w;
      }
    }
    *(float4*)&p[m*4] = make_float4(a0,b0,c0,d0);   // dRG4 -> p row head
  }
}

// ---- descriptor backward via MFMA (r22 staging + r23 dRG4 split):
//      1 atom/block, 128 thr. GT rows + dRG4 async-staged into LDS at entry. ----
__global__ void __launch_bounds__(128) k_bwdm2(const float* __restrict__ sym,
    const float* __restrict__ dxp,const float* __restrict__ dyp,const float* __restrict__ dzp,
    const int* __restrict__ types,
    const float* __restrict__ fw0,const float* __restrict__ fb0,
    const float* __restrict__ fb1,
    float* __restrict__ ws, float* __restrict__ out){
  extern __shared__ char lraw[];
  float* dRG4 = (float*)lraw;                              // staged [100][4] -> 1600
  float* red  = (float*)(lraw + 1600);                     // 16 f
  unsigned short* a2L = (unsigned short*)(lraw + 1664);    // stride 51 -> 14720
  unsigned* dz2u = (unsigned*)(lraw + 14720);              // stride 25
  unsigned short* dz2s = (unsigned short*)(lraw + 14720);  // stride 50
  unsigned* ML = (unsigned*)(lraw + 27648);                // stride 51 -> 54016
  unsigned short* dz1L = (unsigned short*)(lraw + 27648);  // stride 28
  unsigned* GTL = (unsigned*)(lraw + 54016);               // [50][128] -> 79616

  const int bid = blockIdx.x;
  const int b = bid >> 10;
  const int s = threadIdx.x;
  const int wave = s>>6, lane = s&63, lw = lane&15, lg = lane>>4;

  // ---- async-stage GT rows + dRG4 row (both depend only on bid);
  //      fire-and-forget into LDS, drained by the first __syncthreads.
  {
    const unsigned* GTg = (const unsigned*)ws + WS_GTB + (size_t)bid*((HM/2)*NSEL);
    for(int qp = wave; qp < 25; qp += 2){
      __builtin_amdgcn_global_load_lds((GU*)(GTg + qp*256 + lane*4), (LU*)(GTL + qp*256), 16, 0, 0);
    }
    const unsigned* Dg = (const unsigned*)(ws + WS_P + (size_t)bid*GF);
    if(wave==0){
      __builtin_amdgcn_global_load_lds((GU*)(Dg + lane*4), (LU*)((unsigned*)lraw), 16, 0, 0);
    } else if(lane < 36){
      __builtin_amdgcn_global_load_lds((GU*)(Dg + 256 + lane*4), (LU*)((unsigned*)lraw + 256), 16, 0, 0);
    }
  }

  int t = types[bid];
  t = __builtin_amdgcn_readfirstlane(t);
  const float* fin = ws + WS_STATS_FIN + (b*2+t)*8;
  const float avg_s=fin[0], inv_ss=fin[1], inv_sx=fin[2];

  const float* W0 = fw0 + t*H1; const float* B0 = fb0 + t*H1;
  const float* B1f = fb1 + t*H2;
  const unsigned* wsu = (const unsigned*)ws;
  const bf16x8* BF1  = (const bf16x8*)(wsu + WS_BF1B)  + t*4*64;
  const bf16x8* BW2T = (const bf16x8*)(wsu + WS_BW2TB) + t*16*64;
  const bf16x8* BW1T = (const bf16x8*)(wsu + WS_BW1TB) + t*4*64;

  if(s < 32) ((unsigned*)(lraw + 14720))[128*25 + s] = 0;
  if(s < 64) ML[128*51 + s] = 0;

  // ---- B: rn + a1 -> ML rows (uints 0..16)
  float4 R4 = *(const float4*)&sym[(size_t)bid*NSEL*4 + s*4];
  float rn0 = (R4.x-avg_s)*inv_ss, rn1 = R4.y*inv_sx, rn2 = R4.z*inv_sx, rn3 = R4.w*inv_sx;
  {
    float a1r[H1];
#pragma unroll
    for(int kk=0;kk<H1;kk++) a1r[kk] = ftanh(rn0*W0[kk] + B0[kk]);
    unsigned* row = ML + s*51;
#pragma unroll
    for(int q=0;q<12;q++) row[q] = packbf(a1r[2*q], a1r[2*q+1]);
    row[12] = packbf(a1r[24], 0.f);
    row[13]=0; row[14]=0; row[15]=0; row[16]=0;
  }
  __syncthreads();   // a1 frags + staged GT/dRG4 all ready

  const f32x4 fz = {0.f,0.f,0.f,0.f};
  // ---- C: a2 = tanh(a1 @ fw1 + b1) -> a2L (cols < 50 only)
  for(int nt=0;nt<4;nt++){
    f32x4 acc[4];
#pragma unroll
    for(int mt=0;mt<4;mt++){
      bf16x8 af = *(const bf16x8*)&ML[((wave*4+mt)*16+lw)*51 + lg*4];
      acc[mt] = __builtin_amdgcn_mfma_f32_16x16x32_bf16(af, BF1[nt*64+lane], fz, 0,0,0);
    }
    int col = nt*16 + lw;
    if(col < H2){
      float bias = B1f[col];
#pragma unroll
      for(int mt=0;mt<4;mt++)
#pragma unroll
        for(int r=0;r<4;r++){
          int rw = (wave*4+mt)*16 + lg*4 + r;
          a2L[rw*51 + col] = f2bf(ftanh(acc[mt][r] + bias));
        }
    }
  }
  __syncthreads();   // C's a1 reads complete before D overwrites ML
  // ---- D: dz3 -> ML rows; fused drn. GT + dRG4 from LDS.
  float drn0=0,drn1=0,drn2=0,drn3=0;
  {
    unsigned* row = ML + s*51;
    for(int q=0;q<50;q++){
      int m0 = 2*q;
      unsigned u = GTL[q*128 + s];
      float g0 = bflo(u), g1 = bfhi(u);
      float4 dm0 = *(const float4*)&dRG4[m0*4];
      float4 dm1 = *(const float4*)&dRG4[(m0+1)*4];
      drn0 += dm0.x*g0 + dm1.x*g1;
      drn1 += dm0.y*g0 + dm1.y*g1;
      drn2 += dm0.z*g0 + dm1.z*g1;
      drn3 += dm0.w*g0 + dm1.w*g1;
      float d30 = (dm0.x*rn0 + dm0.y*rn1 + dm0.z*rn2 + dm0.w*rn3)*(1.f-g0*g0);
      float d31 = (dm1.x*rn0 + dm1.y*rn1 + dm1.z*rn2 + dm1.w*rn3)*(1.f-g1*g1);
      row[q] = packbf(d30, d31);
    }
    row[50] = 0;
  }
  __syncthreads();   // a2L + dz3 frags ready
  // ---- E: dz2 = dz3 @ fw2^T, deriv vs a2L -> dz2s (cols < 50)
  for(int nt=0;nt<4;nt++){
    f32x4 acc[4];
#pragma unroll
    for(int mt=0;mt<4;mt++) acc[mt] = fz;
    for(int ks=0;ks<4;ks++){
#pragma unroll
      for(int mt=0;mt<4;mt++){
        bf16x8 af = *(const bf16x8*)&ML[((wave*4+mt)*16+lw)*51 + ks*16 + lg*4];
        acc[mt] = __builtin_amdgcn_mfma_f32_16x16x32_bf16(af, BW2T[(nt*4+ks)*64+lane], acc[mt], 0,0,0);
      }
    }
    int col = nt*16 + lw;
    if(col < H2){
#pragma unroll
      for(int mt=0;mt<4;mt++)
#pragma unroll
        for(int r=0;r<4;r++){
          int rw = (wave*4+mt)*16 + lg*4 + r;
          float a2v = bf2f(a2L[rw*51 + col]);
          dz2s[rw*50 + col] = f2bf(acc[mt][r]*(1.f - a2v*a2v));
        }
    }
  }
  __syncthreads();   // dz2s ready; ML (dz3) dead
  // ---- F: dz1 = dz2 @ fw1^T -> dz1L (aliases ML)
  for(int nt2=0;nt2<2;nt2++){
    f32x4 acc[4];
#pragma unroll
    for(int mt=0;mt<4;mt++) acc[mt] = fz;
    for(int ks2=0;ks2<2;ks2++){
#pragma unroll
      for(int mt=0;mt<4;mt++){
        bf16x8 af = *(const bf16x8*)&dz2u[((wave*4+mt)*16+lw)*25 + ks2*16 + lg*4];
        acc[mt] = __builtin_amdgcn_mfma_f32_16x16x32_bf16(af, BW1T[(nt2*2+ks2)*64+lane], acc[mt], 0,0,0);
      }
    }
    int col = nt2*16 + lw;
    if(col < 28){
#pragma unroll
      for(int mt=0;mt<4;mt++)
#pragma unroll
        for(int r=0;r<4;r++){
          int rw = (wave*4+mt)*16 + lg*4 + r;
          dz1L[rw*28 + col] = f2bf((col<H1) ? acc[mt][r] : 0.f);
        }
    }
  }
  __syncthreads();
  // ---- G: ds per row (a1 recomputed from rn0)
  {
    float ds = 0.f;
#pragma unroll
    for(int kk=0;kk<H1;kk++){
      float w0v = W0[kk];
      float a1v = ftanh(rn0*w0v + B0[kk]);
      float d1 = bf2f(dz1L[s*28 + kk]);
      ds += d1*(1.f - a1v*a1v)*w0v;
    }
    drn0 += ds;
  }
  // ---- H: forces
  float w0 = drn0*inv_ss, w1 = drn1*inv_sx, w2 = drn2*inv_sx, w3 = drn3*inv_sx;
  float4 X = *(const float4*)&dxp[(size_t)bid*NSEL*4 + s*4];
  float4 Y = *(const float4*)&dyp[(size_t)bid*NSEL*4 + s*4];
  float4 Z = *(const float4*)&dzp[(size_t)bid*NSEL*4 + s*4];
  float fx = w0*X.x + w1*X.y + w2*X.z + w3*X.w;
  float fy = w0*Y.x + w1*Y.y + w2*Y.z + w3*Y.w;
  float fz2 = w0*Z.x + w1*Z.y + w2*Z.z + w3*Z.w;
  fx = wave_sum(fx); fy = wave_sum(fy); fz2 = wave_sum(fz2);
  __syncthreads();
  if((s&63)==0){ int w=s>>6; red[w*3+0]=fx; red[w*3+1]=fy; red[w*3+2]=fz2; }
  __syncthreads();
  if(s==0){
    float* F = out + 4 + (size_t)bid*3;
    F[0] = -(red[0]+red[3]);
    F[1] = -(red[1]+red[4]);
    F[2] = -(red[2]+red[5]);
  }
}

// ---- scalar fallback backward (recompute G) ----
__global__ void __launch_bounds__(128) k_bwd0(const float* __restrict__ sym,
    const float* __restrict__ dxp,const float* __restrict__ dyp,const float* __restrict__ dzp,
    const int* __restrict__ types,
    const float* __restrict__ fw0,const float* __restrict__ fb0,
    const float* __restrict__ fw1,const float* __restrict__ fb1,
    const float* __restrict__ fb2,
    float* __restrict__ ws, float* __restrict__ out){
  __shared__ float RG4[HM*4];
  __shared__ float dgb[HM*17];
  __shared__ float dRG4[HM*4];
  __shared__ float red[8];

  const int bid = blockIdx.x;
  const int b = bid >> 10;
  int t = types[bid];
  t = __builtin_amdgcn_readfirstlane(t);
  const float* fin = ws + WS_STATS_FIN + (b*2+t)*8;
  const float avg_s=fin[0], inv_ss=fin[1], inv_sx=fin[2], cntf=fin[3];
  const float* mf = ws + WS_MUSD_FIN + (b*2+t)*4;
  const float mu=mf[0], inv_sd=mf[1], rr=mf[2];
  const float S1 = ws[WS_S_RAW + (b*2+t)*2 + 0];
  const float Sy = ws[WS_S_RAW + (b*2+t)*2 + 1];
  const float denom = cntf * (float)GF;
  const float c1 = S1/denom;
  const float c2 = (rr>0.f) ? (Sy/denom)/rr : 0.f;
  const int s = threadIdx.x;

  const float* W0 = fw0 + t*H1; const float* B0 = fb0 + t*H1;
  const float* B1 = fb1 + t*H2; const float* B2 = fb2 + t*HM;
  const float* W1  = fw1 + t*H1*H2;
  const float* W1T = ws + WS_FW1T + t*H2*H1;
  const float* W2T = ws + WS_FW2T + t*HM*H2;

  for(int i=s;i<HM*4;i+=128) RG4[i] = ws[WS_RGB + (size_t)bid*(HM*4) + i];
  __syncthreads();

  const float* p = ws + WS_P + (size_t)bid*GF;
  for(int i=s;i<GF;i+=128){
    int m=i>>4, a=i&15;
    float4 rm = *(const float4*)&RG4[m*4];
    float4 ra = *(const float4*)&RG4[a*4];
    float gv = rm.x*ra.x + rm.y*ra.y + rm.z*ra.z + rm.w*ra.w;
    float yv = (gv-mu)*inv_sd;
    dgb[m*17+a] = (p[i]-c1)*inv_sd - yv*c2;
  }
  __syncthreads();
  if(s < HM){
    const int m = s;
    float a0=0,b0=0,c0=0,d0=0;
#pragma unroll
    for(int a=0;a<AX;a++){
      float d = dgb[m*17+a];
      float4 r = *(const float4*)&RG4[a*4];
      a0 += d*r.x; b0 += d*r.y; c0 += d*r.z; d0 += d*r.w;
    }
    if(m<AX){
      for(int mp=0;mp<HM;mp++){
        float d = dgb[mp*17+m];
        float4 r = *(const float4*)&RG4[mp*4];
        a0 += d*r.x; b0 += d*r.y; c0 += d*r.z; d0 += d*r.w;
      }
    }
    *(float4*)&dRG4[m*4] = make_float4(a0,b0,c0,d0);
  }
  __syncthreads();

  float4 R4 = *(const float4*)&sym[(size_t)bid*NSEL*4 + s*4];
  float rn0 = (R4.x-avg_s)*inv_ss, rn1 = R4.y*inv_sx, rn2 = R4.z*inv_sx, rn3 = R4.w*inv_sx;

  float a1[H1];
#pragma unroll
  for(int kk=0;kk<H1;kk++) a1[kk] = ftanh(rn0*W0[kk] + B0[kk]);
  float a2[H2];
#pragma unroll
  for(int j=0;j<H2;j++){
    float acc = B1[j];
    const float* wr = W1T + j*H1;
#pragma unroll
    for(int kk=0;kk<H1;kk++) acc += a1[kk]*wr[kk];
    a2[j] = ftanh(acc);
  }

  float dz2a[H2];
#pragma unroll
  for(int j=0;j<H2;j++) dz2a[j]=0.f;
  float drn0=0,drn1=0,drn2=0,drn3=0;
  for(int m=0;m<HM;m+=4){
    const float* wr0 = W2T + m*H2; const float* wr1 = wr0 + H2;
    const float* wr2 = wr1 + H2;  const float* wr3 = wr2 + H2;
    float acc0 = B2[m], acc1 = B2[m+1], acc2 = B2[m+2], acc3 = B2[m+3];
#pragma unroll
    for(int j=0;j<H2;j++){
      float aj = a2[j];
      acc0 += aj*wr0[j]; acc1 += aj*wr1[j]; acc2 += aj*wr2[j]; acc3 += aj*wr3[j];
    }
    float g0 = ftanh(acc0), g1 = ftanh(acc1), g2 = ftanh(acc2), g3 = ftanh(acc3);
    float4 d0 = *(const float4*)&dRG4[m*4];
    float4 d1 = *(const float4*)&dRG4[(m+1)*4];
    float4 d2 = *(const float4*)&dRG4[(m+2)*4];
    float4 d3 = *(const float4*)&dRG4[(m+3)*4];
    drn0 += d0.x*g0 + d1.x*g1 + d2.x*g2 + d3.x*g3;
    drn1 += d0.y*g0 + d1.y*g1 + d2.y*g2 + d3.y*g3;
    drn2 += d0.z*g0 + d1.z*g1 + d2.z*g2 + d3.z*g3;
    drn3 += d0.w*g0 + d1.w*g1 + d2.w*g2 + d3.w*g3;
    float dz30 = (d0.x*rn0 + d0.y*rn1 + d0.z*rn2 + d0.w*rn3)*(1.f-g0*g0);
    float dz31 = (d1.x*rn0 + d1.y*rn1 + d1.z*rn2 + d1.w*rn3)*(1.f-g1*g1);
    float dz32 = (d2.x*rn0 + d2.y*rn1 + d2.z*rn2 + d2.w*rn3)*(1.f-g2*g2);
    float dz33 = (d3.x*rn0 + d3.y*rn1 + d3.z*rn2 + d3.w*rn3)*(1.f-g3*g3);
#pragma unroll
    for(int j=0;j<H2;j++) dz2a[j] += dz30*wr0[j] + dz31*wr1[j] + dz32*wr2[j] + dz33*wr3[j];
  }
#pragma unroll
  for(int j=0;j<H2;j++){ float av=a2[j]; dz2a[j] *= (1.f-av*av); }
  float dsacc=0.f;
#pragma unroll
  for(int kk=0;kk<H1;kk++){
    const float* wr = W1 + kk*H2;
    float acc=0.f;
#pragma unroll
    for(int j=0;j<H2;j++) acc += dz2a[j]*wr[j];
    float av=a1[kk];
    dsacc += acc*(1.f-av*av)*W0[kk];
  }
  drn0 += dsacc;
  float w0 = drn0*inv_ss, w1 = drn1*inv_sx, w2 = drn2*inv_sx, w3 = drn3*inv_sx;
  float4 X = *(const float4*)&dxp[(size_t)bid*NSEL*4 + s*4];
  float4 Y = *(const float4*)&dyp[(size_t)bid*NSEL*4 + s*4];
  float4 Z = *(const float4*)&dzp[(size_t)bid*NSEL*4 + s*4];
  float fx = w0*X.x + w1*X.y + w2*X.z + w3*X.w;
  float fy = w0*Y.x + w1*Y.y + w2*Y.z + w3*Y.w;
  float fz = w0*Z.x + w1*Z.y + w2*Z.z + w3*Z.w;
  fx = wave_sum(fx); fy = wave_sum(fy); fz = wave_sum(fz);
  __syncthreads();
  if((s&63)==0){ int w=s>>6; red[w*3+0]=fx; red[w*3+1]=fy; red[w*3+2]=fz; }
  __syncthreads();
  if(s==0){
    float* F = out + 4 + (size_t)bid*3;
    F[0] = -(red[0]+red[3]);
    F[1] = -(red[1]+red[4]);
    F[2] = -(red[2]+red[5]);
  }
}

__global__ void k_write_E(const float* __restrict__ ws, float* __restrict__ out){
  __shared__ float red[8];
  const int b = blockIdx.x;
  const float* e = ws + WS_EBUF + b*NATOM;
  float sv=0;
  for(int i=threadIdx.x;i<NATOM;i+=256) sv+=e[i];
  sv = block_sum4(sv, red);
  if(threadIdx.x==0) out[b]=sv;
}

extern "C" void kernel_launch(void* const* d_in, const int* in_sizes, int n_in,
                              void* d_out, int out_size, void* d_ws, size_t ws_size,
                              hipStream_t stream) {
  const float* sym = (const float*)d_in[0];
  const float* dxp = (const float*)d_in[1];
  const float* dyp = (const float*)d_in[2];
  const float* dzp = (const float*)d_in[3];
  const int*   types=(const int*)d_in[4];
  const float* fw0=(const float*)d_in[5];
  const float* fb0=(const float*)d_in[6];
  const float* fw1=(const float*)d_in[7];
  const float* fb1=(const float*)d_in[8];
  const float* fw2=(const float*)d_in[9];
  const float* fb2=(const float*)d_in[10];
  const float* gw0=(const float*)d_in[11];
  const float* gb0=(const float*)d_in[12];
  const float* gw1=(const float*)d_in[13];
  const float* gb1=(const float*)d_in[14];
  const float* gw2=(const float*)d_in[15];
  const float* gb2=(const float*)d_in[16];
  const float* gwo=(const float*)d_in[17];
  const float* gbo=(const float*)d_in[18];
  float* ws = (float*)d_ws;
  float* out = (float*)d_out;

  const size_t need_bytes = (size_t)WS_END * 4;
  const int storeGT = (ws_size >= need_bytes) ? 1 : 0;

  hipMemsetAsync(d_ws, 0, 1024, stream);
  hipMemsetAsync((char*)d_ws + (size_t)WS_IDX*4, 0xFF, (size_t)NBATCH*1152*4, stream);

  k_transpose<<<1024,256,0,stream>>>(gw0,gw1,gw2,fw1,fw2,ws);
  if(storeGT) k_packf<<<64,256,0,stream>>>(fw1,fw2,ws);
  k_stats<<<dim3(16,NBATCH),256,0,stream>>>(sym,types,ws);
  k_fin_stats<<<1,64,0,stream>>>(ws);
  k_index<<<NBATCH,256,0,stream>>>(types,ws);

  if(storeGT){
    const int lds_fwdm = 48224;
    hipFuncSetAttribute((const void*)k_fwdm, hipFuncAttributeMaxDynamicSharedMemorySize, lds_fwdm);
    k_fwdm<<<NBATCH*NATOM,128,lds_fwdm,stream>>>(sym,types,fw0,fb0,fb1,fb2,ws);
  } else {
    k_fwd<<<NBATCH*NATOM,128,0,stream>>>(sym,types,fw0,fb0,fb1,fb2,ws);
  }
  k_fin_musd<<<1,64,0,stream>>>(ws);

  const int lds_fitm = 3*64*264*2;   // 101376 B
  hipFuncSetAttribute((const void*)k_fitm, hipFuncAttributeMaxDynamicSharedMemorySize, lds_fitm);
  k_fitm<<<NBATCH*NGRP64,256,lds_fitm,stream>>>(gb0,gb1,gb2,gwo,gbo,ws);

  const int lds_pm = 64*264*2;       // 33792 B
  hipFuncSetAttribute((const void*)k_pm, hipFuncAttributeMaxDynamicSharedMemorySize, lds_pm);
  k_pm<<<NBATCH*NGRP64*PCH,256,lds_pm,stream>>>(ws);

  if(storeGT){
    k_dgb<<<NBATCH*NATOM,128,0,stream>>>(types,ws);
    const int lds_bwdm = 79616;
    hipFuncSetAttribute((const void*)k_bwdm2, hipFuncAttributeMaxDynamicSharedMemorySize, lds_bwdm);
    k_bwdm2<<<NBATCH*NATOM,128,lds_bwdm,stream>>>(sym,dxp,dyp,dzp,types,fw0,fb0,fb1,ws,out);
  } else {
    k_bwd0<<<NBATCH*NATOM,128,0,stream>>>(sym,dxp,dyp,dzp,types,fw0,fb0,fw1,fb1,fb2,ws,out);
  }

  k_write_E<<<NBATCH,256,0,stream>>>(ws,out);
}